// Round 6
// baseline (196.965 us; speedup 1.0000x reference)
//
#include <hip/hip_runtime.h>
#include <stdint.h>

// B=32, La=512, Lq=64, H=1024. Score path split-bf16 (3 MFMA), value path bf16.
// Single-buffered GEMMs (R4 structure: occupancy > source pipelining on this HW).
// g1: Pcat = Q(split)@Wcat^T (128x128 tile, remap) || P3T = (Q@W21)^T   [768 blocks]
// g2: score partials = A(split reg-staged)@Pcat^T, K-split x2            [512 blocks]
// softmax_rows: aq = rowsoftmax(Sp0+Sp1 cols 0..63)  bf16
// softmax_cols: qa = colsoftmax(Sp0+Sp1 cols 64..127) bf16
// g3: PmaxA = colmax(relu(aq@P3T^T)) || ctx = qa@A (A fp32 reg-staged)
// g4: PmaxQ = colmax64(relu(ctx@W22T^T))
// final: out = 0.5*max4(PmaxA) + 0.5*PmaxQ

using bf16x8 = __attribute__((ext_vector_type(8))) short;
using f32x4  = __attribute__((ext_vector_type(4))) float;
typedef const __attribute__((address_space(1))) void* gas_t;
typedef __attribute__((address_space(3))) void* las_t;

__device__ __forceinline__ unsigned short f2bf(float x) {
  unsigned u = __builtin_bit_cast(unsigned, x);
  u += 0x7fffu + ((u >> 16) & 1u);
  return (unsigned short)(u >> 16);
}
__device__ __forceinline__ float bf2f(unsigned short h) {
  unsigned u = ((unsigned)h) << 16;
  return __builtin_bit_cast(float, u);
}

// ---------------- prep ----------------

__global__ __launch_bounds__(256) void conv_split(const float* __restrict__ in,
    unsigned short* __restrict__ hi, unsigned short* __restrict__ lo, int n4)
{
  int i = blockIdx.x * 256 + threadIdx.x;
  if (i >= n4) return;
  float4 v = ((const float4*)in)[i];
  ushort4 h, l;
  h.x = f2bf(v.x); l.x = f2bf(v.x - bf2f(h.x));
  h.y = f2bf(v.y); l.y = f2bf(v.y - bf2f(h.y));
  h.z = f2bf(v.z); l.z = f2bf(v.z - bf2f(h.z));
  h.w = f2bf(v.w); l.w = f2bf(v.w - bf2f(h.w));
  ((ushort4*)hi)[i] = h;
  ((ushort4*)lo)[i] = l;
}

// z=0: W11 split straight; z=1: W12 transpose-split; z=2: W21T; z=3: W22T
__global__ __launch_bounds__(256) void prep_W(
    const float* __restrict__ W11, const float* __restrict__ W12,
    const float* __restrict__ W21, const float* __restrict__ W22,
    unsigned short* __restrict__ Wcat_hi, unsigned short* __restrict__ Wcat_lo,
    unsigned short* __restrict__ W21T, unsigned short* __restrict__ W22T)
{
  __shared__ float tile[32][33];
  int z = blockIdx.z;
  const float* src = z == 0 ? W11 : z == 1 ? W12 : z == 2 ? W21 : W22;
  int r0 = blockIdx.y * 32, c0 = blockIdx.x * 32;
  int tx = threadIdx.x, ty = threadIdx.y;
  #pragma unroll
  for (int i = 0; i < 4; ++i) {
    int r = r0 + ty + i * 8;
    float v = src[(long)r * 1024 + c0 + tx];
    tile[ty + i * 8][tx] = v;
    if (z == 0) {
      long o = (long)r * 1024 + c0 + tx;
      unsigned short h = f2bf(v);
      Wcat_hi[o] = h;
      Wcat_lo[o] = f2bf(v - bf2f(h));
    }
  }
  __syncthreads();
  if (z > 0) {
    #pragma unroll
    for (int i = 0; i < 4; ++i) {
      float v = tile[tx][ty + i * 8];
      long o = (long)(c0 + ty + i * 8) * 1024 + r0 + tx;
      unsigned short h = f2bf(v);
      if (z == 1) {
        Wcat_hi[1048576 + o] = h;
        Wcat_lo[1048576 + o] = f2bf(v - bf2f(h));
      } else if (z == 2) W21T[o] = h;
      else W22T[o] = h;
    }
  }
}

// ---------------- generic MFMA GEMM body (C = A @ B^T), single-buffered ----------------
// OUT: 1=Pcat split remap, 2=bf16 (row<M), 3=P3T transpose, 4=relu+colmax(BM),
// 5=relu+colmax per 64 rows. BF32: B operand is fp32 [K x ldB] (k-major), reg-staged.
template<int BM, int BN, bool SPLIT, int OUT, bool BF32>
__device__ __forceinline__ void gemm_body(
    char* smem, int bx, int by, int z,
    const unsigned short* __restrict__ Ah, const unsigned short* __restrict__ Al,
    const unsigned short* __restrict__ Bh, const unsigned short* __restrict__ Bl,
    const float* __restrict__ Bf,
    float* __restrict__ Cf, unsigned short* __restrict__ Ch, unsigned short* __restrict__ Cl,
    int M, int N, int K, int ldA, int ldB, int ldC, long sA, long sB, long sC, int mtiles)
{
  constexpr int AB = BM * 64, BB = BN * 64;
  constexpr int MI = BM / 32, NI = BN / 32;
  char* As  = smem;
  char* Asl = SPLIT ? smem + AB : nullptr;
  char* Bs  = smem + (SPLIT ? 2 * AB : AB);
  char* Bsl = SPLIT ? Bs + BB : nullptr;

  const int m0 = by * BM, n0 = bx * BN;
  const int t = threadIdx.x, lane = t & 63;
  const int wid = t >> 6, wr = wid >> 1, wc = wid & 1;

  const unsigned short* Ab  = Ah + (long)z * sA;
  const unsigned short* Bb  = BF32 ? nullptr : Bh + (long)z * sB;
  const unsigned short* Abl = SPLIT ? Al + (long)z * sA : nullptr;
  const unsigned short* Bbl = SPLIT ? Bl + (long)z * sB : nullptr;
  const float* Bfb = BF32 ? Bf + (long)z * sB : nullptr;

  f32x4 acc[MI][NI];
  #pragma unroll
  for (int i = 0; i < MI; ++i)
    #pragma unroll
    for (int j = 0; j < NI; ++j)
      acc[i][j] = f32x4{0.f, 0.f, 0.f, 0.f};

  auto stage4k = [&](char* lbuf, const unsigned short* g, int ld, int row0, int k0, int rmax) {
    int ob = t * 16;
    int e  = ob ^ (((ob >> 7) & 3) << 4);
    int m  = e >> 6, k = (e & 63) >> 1;
    int row = row0 + m; row = row < rmax ? row : rmax - 1;
    const unsigned short* gp = g + (long)row * ld + k0 + k;
    char* lp = lbuf + (t & ~63) * 16;  // wave-uniform; HW adds lane*16
    __builtin_amdgcn_global_load_lds((gas_t)(const void*)gp, (las_t)(void*)lp, 16, 0, 0);
  };
  // B tile [BN n x 32 k] from fp32 source B[k, n] (k-major): transpose + convert
  auto stageB_f32 = [&](char* lbuf, const float* g, int ld, int nb, int k0) {
    int ob = t * 16;
    int e  = ob ^ (((ob >> 7) & 3) << 4);
    int n  = e >> 6, kb = (e & 63) >> 1;
    bf16x8 pk;
    #pragma unroll
    for (int j = 0; j < 8; ++j) {
      float v = g[(long)(k0 + kb + j) * ld + nb + n];
      pk[j] = (short)f2bf(v);
    }
    *(bf16x8*)(lbuf + ob) = pk;
  };
  auto ldfrag = [&](const char* lbuf, int rr) -> bf16x8 {
    int ob = rr * 64 + (lane >> 4) * 16;
    ob ^= ((ob >> 7) & 3) << 4;
    return *(const bf16x8*)(lbuf + ob);
  };

  for (int k0 = 0; k0 < K; k0 += 32) {
    stage4k(As, Ab, ldA, m0, k0, M);
    if (BM == 128) stage4k(As + 4096, Ab, ldA, m0 + 64, k0, M);
    if (BF32) {
      stageB_f32(Bs, Bfb, ldB, n0, k0);
    } else {
      stage4k(Bs, Bb, ldB, n0, k0, N);
      if (BN == 128) stage4k(Bs + 4096, Bb, ldB, n0 + 64, k0, N);
    }
    if (SPLIT) {
      stage4k(Asl, Abl, ldA, m0, k0, M);
      if (BM == 128) stage4k(Asl + 4096, Abl, ldA, m0 + 64, k0, M);
      stage4k(Bsl, Bbl, ldB, n0, k0, N);
      if (BN == 128) stage4k(Bsl + 4096, Bbl, ldB, n0 + 64, k0, N);
    }
    __syncthreads();

    bf16x8 ah[MI], al[MI];
    #pragma unroll
    for (int mi = 0; mi < MI; ++mi) {
      int rr = wr * (BM / 2) + mi * 16 + (lane & 15);
      ah[mi] = ldfrag(As, rr);
      if (SPLIT) al[mi] = ldfrag(Asl, rr);
    }
    #pragma unroll
    for (int ni = 0; ni < NI; ++ni) {
      int rc = wc * (BN / 2) + ni * 16 + (lane & 15);
      bf16x8 bh = ldfrag(Bs, rc);
      bf16x8 bl;
      if (SPLIT) bl = ldfrag(Bsl, rc);
      #pragma unroll
      for (int mi = 0; mi < MI; ++mi) {
        acc[mi][ni] = __builtin_amdgcn_mfma_f32_16x16x32_bf16(ah[mi], bh, acc[mi][ni], 0, 0, 0);
        if (SPLIT) {
          acc[mi][ni] = __builtin_amdgcn_mfma_f32_16x16x32_bf16(ah[mi], bl, acc[mi][ni], 0, 0, 0);
          acc[mi][ni] = __builtin_amdgcn_mfma_f32_16x16x32_bf16(al[mi], bh, acc[mi][ni], 0, 0, 0);
        }
      }
    }
    __syncthreads();
  }

  if (OUT == 4 || OUT == 5) {
    float* red = (float*)smem;  // safe: k-loop ended with __syncthreads
    #pragma unroll
    for (int ni = 0; ni < NI; ++ni) {
      float pm = 0.0f;  // relu floor
      #pragma unroll
      for (int mi = 0; mi < MI; ++mi)
        #pragma unroll
        for (int r = 0; r < 4; ++r)
          pm = fmaxf(pm, acc[mi][ni][r]);
      int g = wr * 4 + (lane >> 4);
      int col = wc * (BN / 2) + ni * 16 + (lane & 15);
      red[g * BN + col] = pm;
    }
    __syncthreads();
    if (OUT == 4) {
      if (t < BN) {
        float m = red[t];
        #pragma unroll
        for (int g = 1; g < 8; ++g) m = fmaxf(m, red[g * BN + t]);
        Cf[(long)(z * mtiles + by) * ldC + n0 + t] = m;
      }
    } else {
      constexpr int NGR = BM / 64, PG = 8 / NGR;
      if (t < NGR * BN) {
        int hh = t / BN, col = t - hh * BN;
        float m = red[(hh * PG) * BN + col];
        #pragma unroll
        for (int i = 1; i < PG; ++i) m = fmaxf(m, red[(hh * PG + i) * BN + col]);
        Cf[(long)((m0 >> 6) + hh) * ldC + n0 + col] = m;
      }
    }
    return;
  }

  #pragma unroll
  for (int mi = 0; mi < MI; ++mi) {
    #pragma unroll
    for (int r = 0; r < 4; ++r) {
      int grow = m0 + wr * (BM / 2) + mi * 16 + (lane >> 4) * 4 + r;
      #pragma unroll
      for (int ni = 0; ni < NI; ++ni) {
        int gcol = n0 + wc * (BN / 2) + ni * 16 + (lane & 15);
        float v = acc[mi][ni][r];
        if (OUT == 1) {
          int b = grow >> 6, q = grow & 63;
          long dst = (long)b * 131072 + (long)((gcol >> 10) * 64 + q) * 1024 + (gcol & 1023);
          unsigned short h = f2bf(v);
          Ch[dst] = h;
          Cl[dst] = f2bf(v - bf2f(h));
        } else if (OUT == 2) {
          if (grow < M) Ch[(long)z * sC + (long)grow * ldC + gcol] = f2bf(v);
        } else if (OUT == 3) {
          long dst = (long)(grow >> 6) * 65536 + (long)gcol * 64 + (grow & 63);
          Ch[dst] = f2bf(v);
        }
      }
    }
  }
}

// ---------------- g1: Pcat (128x128) || P3T (64x64), 768 blocks, XCD-chunked ----------------

__global__ __launch_bounds__(256) void g1_kernel(
    const unsigned short* Q_hi, const unsigned short* Q_lo,
    const unsigned short* Wcat_hi, const unsigned short* Wcat_lo,
    const unsigned short* W21T,
    unsigned short* Pcat_hi, unsigned short* Pcat_lo, unsigned short* P3T)
{
  __shared__ char smem[32768];
  int bid = (blockIdx.x & 7) * 96 + (blockIdx.x >> 3);  // bijective, 768 % 8 == 0
  if (bid < 256) {   // Pcat: M=2048,N=2048,K=1024, tile 128x128, split
    gemm_body<128, 128, true, 1, false>(smem, bid & 15, bid >> 4, 0,
        Q_hi, Q_lo, Wcat_hi, Wcat_lo, nullptr, nullptr, Pcat_hi, Pcat_lo,
        2048, 2048, 1024, 1024, 1024, 0, 0, 0, 0, 0);
  } else {           // P3T: M=2048,N=1024,K=1024, tile 64x64
    int b2 = bid - 256;
    gemm_body<64, 64, false, 3, false>(smem, b2 & 15, b2 >> 4, 0,
        Q_hi, nullptr, W21T, nullptr, nullptr, nullptr, P3T, nullptr,
        2048, 1024, 1024, 1024, 1024, 0, 0, 0, 0, 0);
  }
}

// ---------------- g2: score partials, tile 64x128, 8 waves, K-split x2 ----------------

__global__ __launch_bounds__(512) void g2_kernel(
    const float* __restrict__ Afeat,
    const unsigned short* __restrict__ Pcat_hi, const unsigned short* __restrict__ Pcat_lo,
    float* __restrict__ Spar)
{
  __shared__ char smem[24576];
  char* Ash = smem;           // 4KB
  char* Asl = smem + 4096;    // 4KB
  char* Bs  = smem + 8192;    // 8KB
  char* Bsl = smem + 16384;   // 8KB

  int orig = blockIdx.x;            // 512 blocks
  int xcd = orig & 7, idx = orig >> 3;
  int z   = xcd * 4 + (idx >> 4);   // 4 batches per XCD -> Pcat L2-resident
  int sub = idx & 15;
  int by  = sub >> 1, kh = sub & 1;
  const int m0 = by * 64, kb = kh * 512;
  const int t = threadIdx.x, lane = t & 63;
  const int wid = t >> 6, wr = wid >> 1, wc = wid & 1;

  const float* Ab = Afeat + (long)z * 524288;
  const unsigned short* Bbh = Pcat_hi + (long)z * 131072;
  const unsigned short* Bbl = Pcat_lo + (long)z * 131072;

  f32x4 acc[4];
  #pragma unroll
  for (int i = 0; i < 4; ++i) acc[i] = f32x4{0.f, 0.f, 0.f, 0.f};

  auto ldfrag = [&](const char* lbuf, int rr) -> bf16x8 {
    int ob = rr * 64 + (lane >> 4) * 16;
    ob ^= ((ob >> 7) & 3) << 4;
    return *(const bf16x8*)(lbuf + ob);
  };

  for (int k0 = kb; k0 < kb + 512; k0 += 32) {
    { // A: fp32 load + split + ds_write (8B hi + 8B lo per thread)
      int ob = t * 8;
      int e  = ob ^ (((ob >> 7) & 3) << 4);
      int m  = e >> 6, ke = (e & 63) >> 1;
      float4 v = *(const float4*)(Ab + (long)(m0 + m) * 1024 + k0 + ke);
      ushort4 h, l;
      h.x = f2bf(v.x); l.x = f2bf(v.x - bf2f(h.x));
      h.y = f2bf(v.y); l.y = f2bf(v.y - bf2f(h.y));
      h.z = f2bf(v.z); l.z = f2bf(v.z - bf2f(h.z));
      h.w = f2bf(v.w); l.w = f2bf(v.w - bf2f(h.w));
      *(ushort4*)(Ash + ob) = h;
      *(ushort4*)(Asl + ob) = l;
    }
    { // B: gload hi+lo, 8KB each (512 threads x 16B)
      int ob = t * 16;
      int e  = ob ^ (((ob >> 7) & 3) << 4);
      int n  = e >> 6, kk = (e & 63) >> 1;
      const unsigned short* gp  = Bbh + (long)n * 1024 + k0 + kk;
      const unsigned short* gpl = Bbl + (long)n * 1024 + k0 + kk;
      char* lp  = Bs  + (t & ~63) * 16;
      char* lpl = Bsl + (t & ~63) * 16;
      __builtin_amdgcn_global_load_lds((gas_t)(const void*)gp,  (las_t)(void*)lp,  16, 0, 0);
      __builtin_amdgcn_global_load_lds((gas_t)(const void*)gpl, (las_t)(void*)lpl, 16, 0, 0);
    }
    __syncthreads();

    bf16x8 ah  = ldfrag(Ash, wr * 16 + (lane & 15));
    bf16x8 alo = ldfrag(Asl, wr * 16 + (lane & 15));
    #pragma unroll
    for (int ni = 0; ni < 4; ++ni) {
      bf16x8 bh = ldfrag(Bs,  wc * 64 + ni * 16 + (lane & 15));
      bf16x8 bl = ldfrag(Bsl, wc * 64 + ni * 16 + (lane & 15));
      acc[ni] = __builtin_amdgcn_mfma_f32_16x16x32_bf16(ah,  bh, acc[ni], 0, 0, 0);
      acc[ni] = __builtin_amdgcn_mfma_f32_16x16x32_bf16(ah,  bl, acc[ni], 0, 0, 0);
      acc[ni] = __builtin_amdgcn_mfma_f32_16x16x32_bf16(alo, bh, acc[ni], 0, 0, 0);
    }
    __syncthreads();
  }

  // write fp32 partial scores
  float* dst = Spar + (long)kh * 2097152 + (long)z * 65536;
  #pragma unroll
  for (int r = 0; r < 4; ++r) {
    int grow = m0 + wr * 16 + (lane >> 4) * 4 + r;
    long base = (long)grow * 128 + wc * 64 + (lane & 15);
    dst[base]      = acc[0][r];
    dst[base + 16] = acc[1][r];
    dst[base + 32] = acc[2][r];
    dst[base + 48] = acc[3][r];
  }
}

// ---------------- softmaxes over partial sums ----------------

__global__ __launch_bounds__(256) void softmax_rows(const float* __restrict__ Sp,
                                                    unsigned short* __restrict__ aq)
{
  int row  = blockIdx.x * 4 + (threadIdx.x >> 6);
  int lane = threadIdx.x & 63;
  long o = (long)row * 128 + lane;
  float v = Sp[o] + Sp[o + 2097152];
  float m = v;
  #pragma unroll
  for (int off = 32; off; off >>= 1) m = fmaxf(m, __shfl_xor(m, off));
  float e = __expf(v - m);
  float s = e;
  #pragma unroll
  for (int off = 32; off; off >>= 1) s += __shfl_xor(s, off);
  aq[(long)row * 64 + lane] = f2bf(e / s);
}

__global__ __launch_bounds__(256) void softmax_cols(const float* __restrict__ Sp,
                                                    unsigned short* __restrict__ qa)
{
  int bq = blockIdx.x;
  int b = bq >> 6, q = bq & 63;
  int t = threadIdx.x;
  const float* base = Sp + (long)b * 65536 + 64 + q;
  float v0 = base[(long)t * 128]         + base[(long)t * 128 + 2097152];
  float v1 = base[(long)(t + 256) * 128] + base[(long)(t + 256) * 128 + 2097152];
  float m = fmaxf(v0, v1);
  #pragma unroll
  for (int off = 32; off; off >>= 1) m = fmaxf(m, __shfl_xor(m, off));
  __shared__ float sm[4], ss[4];
  int wid = t >> 6, lane = t & 63;
  if (lane == 0) sm[wid] = m;
  __syncthreads();
  float M = fmaxf(fmaxf(sm[0], sm[1]), fmaxf(sm[2], sm[3]));
  float e0 = __expf(v0 - M), e1 = __expf(v1 - M);
  float s = e0 + e1;
  #pragma unroll
  for (int off = 32; off; off >>= 1) s += __shfl_xor(s, off);
  if (lane == 0) ss[wid] = s;
  __syncthreads();
  float inv = 1.0f / ((ss[0] + ss[1]) + (ss[2] + ss[3]));
  qa[(long)bq * 512 + t]       = f2bf(e0 * inv);
  qa[(long)bq * 512 + t + 256] = f2bf(e1 * inv);
}

// ---------------- g3: PmaxA || ctx (chunked swizzle, 1536 % 8 == 0) ----------------

__global__ __launch_bounds__(256) void g3_kernel(
    const unsigned short* aq, const unsigned short* P3T, float* PmaxA,
    const unsigned short* qa, const float* Afeat, unsigned short* ctx)
{
  __shared__ char smem[16384];
  int bid = (blockIdx.x & 7) * 192 + (blockIdx.x >> 3);
  if (bid < 1024) {  // PmaxA: per batch M=512,N=1024,K=64, tile 128x128
    gemm_body<128, 128, false, 4, false>(smem, bid & 7, (bid >> 3) & 3, bid >> 5,
        aq, nullptr, P3T, nullptr, nullptr, PmaxA, nullptr, nullptr,
        512, 1024, 64, 64, 64, 1024, 32768L, 65536L, 0, 4);
  } else {           // ctx: per batch M=64,N=1024,K=512, tile 64x64, B = A fp32 (k-major)
    int b2 = bid - 1024;
    gemm_body<64, 64, false, 2, true>(smem, b2 & 15, 0, b2 >> 4,
        qa, nullptr, nullptr, nullptr, Afeat, nullptr, ctx, nullptr,
        64, 1024, 512, 512, 1024, 1024, 32768L, 524288L, 65536L, 0);
  }
}

// ---------------- g4 + final ----------------

__global__ __launch_bounds__(256) void g4_kernel(
    const unsigned short* ctx, const unsigned short* W22T, float* PmaxQ)
{
  __shared__ char smem[8192];
  gemm_body<64, 64, false, 5, false>(smem, blockIdx.x, blockIdx.y, 0,
      ctx, nullptr, W22T, nullptr, nullptr, PmaxQ, nullptr, nullptr,
      2048, 1024, 1024, 1024, 1024, 1024, 0, 0, 0, 0);
}

__global__ __launch_bounds__(256) void final_combine(
    const float* __restrict__ PmaxA, const float* __restrict__ PmaxQ, float* __restrict__ out)
{
  int idx = blockIdx.x * 256 + threadIdx.x;  // 32768
  int b = idx >> 10, h = idx & 1023;
  float m = PmaxA[(long)(b * 4) * 1024 + h];
  #pragma unroll
  for (int mt = 1; mt < 4; ++mt)
    m = fmaxf(m, PmaxA[(long)(b * 4 + mt) * 1024 + h]);
  out[idx] = 0.5f * m + 0.5f * PmaxQ[idx];
}

// ---------------- launch ----------------

extern "C" void kernel_launch(void* const* d_in, const int* in_sizes, int n_in,
                              void* d_out, int out_size, void* d_ws, size_t ws_size,
                              hipStream_t stream) {
  const float* Afeat = (const float*)d_in[0];
  const float* Qfeat = (const float*)d_in[1];
  const float* W11   = (const float*)d_in[2];
  const float* W12   = (const float*)d_in[3];
  const float* W21   = (const float*)d_in[4];
  const float* W22   = (const float*)d_in[5];
  float* out = (float*)d_out;

  char* w = (char*)d_ws;
  auto alloc = [&](long bytes) { char* p = w; w += bytes; return p; };
  unsigned short* Q_hi    = (unsigned short*)alloc(4194304);
  unsigned short* Q_lo    = (unsigned short*)alloc(4194304);
  unsigned short* Wcat_hi = (unsigned short*)alloc(4194304);   // [2048][1024]
  unsigned short* Wcat_lo = (unsigned short*)alloc(4194304);
  unsigned short* W21T    = (unsigned short*)alloc(2097152);
  unsigned short* W22T    = (unsigned short*)alloc(2097152);
  unsigned short* Pcat_hi = (unsigned short*)alloc(8388608);   // [32][128][1024]
  unsigned short* Pcat_lo = (unsigned short*)alloc(8388608);
  unsigned short* P3T     = (unsigned short*)alloc(4194304);   // [32][1024][64]
  float*          Spar    = (float*)alloc(16777216);           // [2][32][512][128]
  unsigned short* aq      = (unsigned short*)alloc(2097152);   // [32][512][64]
  unsigned short* qa      = (unsigned short*)alloc(2097152);   // [32][64][512]
  unsigned short* ctx     = (unsigned short*)alloc(4194304);   // [32][64][1024]
  float*          PmaxA   = (float*)alloc(524288);             // [128][1024]
  float*          PmaxQ   = (float*)alloc(131072);             // [32][1024]

  dim3 blk(256), tblk(32, 8);

  conv_split<<<2048, blk, 0, stream>>>(Qfeat, Q_hi, Q_lo, 524288);
  prep_W<<<dim3(32, 32, 4), tblk, 0, stream>>>(W11, W12, W21, W22, Wcat_hi, Wcat_lo, W21T, W22T);

  g1_kernel<<<768, blk, 0, stream>>>(Q_hi, Q_lo, Wcat_hi, Wcat_lo, W21T, Pcat_hi, Pcat_lo, P3T);
  g2_kernel<<<512, dim3(512), 0, stream>>>(Afeat, Pcat_hi, Pcat_lo, Spar);
  softmax_rows<<<4096, blk, 0, stream>>>(Spar, aq);
  softmax_cols<<<2048, blk, 0, stream>>>(Spar, qa);
  g3_kernel<<<1536, blk, 0, stream>>>(aq, P3T, PmaxA, qa, Afeat, ctx);
  g4_kernel<<<dim3(16, 32), blk, 0, stream>>>(ctx, W22T, PmaxQ);
  final_combine<<<128, blk, 0, stream>>>(PmaxA, PmaxQ, out);
}

// Round 7
// 142.892 us; speedup vs baseline: 1.3784x; 1.3784x over previous
//
#include <hip/hip_runtime.h>
#include <stdint.h>

// B=32, La=512, Lq=64, H=1024. Score path split-bf16 (3 MFMA), value path bf16.
// Single-buffered GEMMs; NATURAL block order everywhere (heterogeneous dispatches
// must round-robin across XCDs — chunked swizzle serializes work types, R6 lesson).
// g1: Pcat = Q(split)@Wcat^T (128x64, remap) || P3T = (Q@W21)^T   [1024 blocks]
// g2: score partials = A(split reg-staged)@Pcat^T, K-split x2      [512 blocks]
// softmax_rows: aq = rowsoftmax(Sp0+Sp1 cols 0..63)  bf16
// softmax_cols: qa = colsoftmax(Sp0+Sp1 cols 64..127) bf16
// g3: PmaxA = colmax(relu(aq@P3T^T)) || ctx = qa@A (A fp32 reg-staged)
// g4: PmaxQ = colmax64(relu(ctx@W22T^T))
// final: out = 0.5*max4(PmaxA) + 0.5*PmaxQ

using bf16x8 = __attribute__((ext_vector_type(8))) short;
using f32x4  = __attribute__((ext_vector_type(4))) float;
typedef const __attribute__((address_space(1))) void* gas_t;
typedef __attribute__((address_space(3))) void* las_t;

__device__ __forceinline__ unsigned short f2bf(float x) {
  unsigned u = __builtin_bit_cast(unsigned, x);
  u += 0x7fffu + ((u >> 16) & 1u);
  return (unsigned short)(u >> 16);
}
__device__ __forceinline__ float bf2f(unsigned short h) {
  unsigned u = ((unsigned)h) << 16;
  return __builtin_bit_cast(float, u);
}

// ---------------- prep ----------------

__global__ __launch_bounds__(256) void conv_split(const float* __restrict__ in,
    unsigned short* __restrict__ hi, unsigned short* __restrict__ lo, int n4)
{
  int i = blockIdx.x * 256 + threadIdx.x;
  if (i >= n4) return;
  float4 v = ((const float4*)in)[i];
  ushort4 h, l;
  h.x = f2bf(v.x); l.x = f2bf(v.x - bf2f(h.x));
  h.y = f2bf(v.y); l.y = f2bf(v.y - bf2f(h.y));
  h.z = f2bf(v.z); l.z = f2bf(v.z - bf2f(h.z));
  h.w = f2bf(v.w); l.w = f2bf(v.w - bf2f(h.w));
  ((ushort4*)hi)[i] = h;
  ((ushort4*)lo)[i] = l;
}

// z=0: W11 split straight; z=1: W12 transpose-split; z=2: W21T; z=3: W22T
__global__ __launch_bounds__(256) void prep_W(
    const float* __restrict__ W11, const float* __restrict__ W12,
    const float* __restrict__ W21, const float* __restrict__ W22,
    unsigned short* __restrict__ Wcat_hi, unsigned short* __restrict__ Wcat_lo,
    unsigned short* __restrict__ W21T, unsigned short* __restrict__ W22T)
{
  __shared__ float tile[32][33];
  int z = blockIdx.z;
  const float* src = z == 0 ? W11 : z == 1 ? W12 : z == 2 ? W21 : W22;
  int r0 = blockIdx.y * 32, c0 = blockIdx.x * 32;
  int tx = threadIdx.x, ty = threadIdx.y;
  #pragma unroll
  for (int i = 0; i < 4; ++i) {
    int r = r0 + ty + i * 8;
    float v = src[(long)r * 1024 + c0 + tx];
    tile[ty + i * 8][tx] = v;
    if (z == 0) {
      long o = (long)r * 1024 + c0 + tx;
      unsigned short h = f2bf(v);
      Wcat_hi[o] = h;
      Wcat_lo[o] = f2bf(v - bf2f(h));
    }
  }
  __syncthreads();
  if (z > 0) {
    #pragma unroll
    for (int i = 0; i < 4; ++i) {
      float v = tile[tx][ty + i * 8];
      long o = (long)(c0 + ty + i * 8) * 1024 + r0 + tx;
      unsigned short h = f2bf(v);
      if (z == 1) {
        Wcat_hi[1048576 + o] = h;
        Wcat_lo[1048576 + o] = f2bf(v - bf2f(h));
      } else if (z == 2) W21T[o] = h;
      else W22T[o] = h;
    }
  }
}

// ---------------- generic MFMA GEMM body (C = A @ B^T), single-buffered ----------------
// OUT: 1=Pcat split remap, 2=bf16 (row<M), 3=P3T transpose, 4=relu+colmax(BM),
// 5=relu+colmax per 64 rows. BF32: B operand is fp32 [K x ldB] (k-major), reg-staged.
template<int BM, int BN, bool SPLIT, int OUT, bool BF32>
__device__ __forceinline__ void gemm_body(
    char* smem, int bx, int by, int z,
    const unsigned short* __restrict__ Ah, const unsigned short* __restrict__ Al,
    const unsigned short* __restrict__ Bh, const unsigned short* __restrict__ Bl,
    const float* __restrict__ Bf,
    float* __restrict__ Cf, unsigned short* __restrict__ Ch, unsigned short* __restrict__ Cl,
    int M, int N, int K, int ldA, int ldB, int ldC, long sA, long sB, long sC, int mtiles)
{
  constexpr int AB = BM * 64, BB = BN * 64;
  constexpr int MI = BM / 32, NI = BN / 32;
  char* As  = smem;
  char* Asl = SPLIT ? smem + AB : nullptr;
  char* Bs  = smem + (SPLIT ? 2 * AB : AB);
  char* Bsl = SPLIT ? Bs + BB : nullptr;

  const int m0 = by * BM, n0 = bx * BN;
  const int t = threadIdx.x, lane = t & 63;
  const int wid = t >> 6, wr = wid >> 1, wc = wid & 1;

  const unsigned short* Ab  = Ah + (long)z * sA;
  const unsigned short* Bb  = BF32 ? nullptr : Bh + (long)z * sB;
  const unsigned short* Abl = SPLIT ? Al + (long)z * sA : nullptr;
  const unsigned short* Bbl = SPLIT ? Bl + (long)z * sB : nullptr;
  const float* Bfb = BF32 ? Bf + (long)z * sB : nullptr;

  f32x4 acc[MI][NI];
  #pragma unroll
  for (int i = 0; i < MI; ++i)
    #pragma unroll
    for (int j = 0; j < NI; ++j)
      acc[i][j] = f32x4{0.f, 0.f, 0.f, 0.f};

  auto stage4k = [&](char* lbuf, const unsigned short* g, int ld, int row0, int k0, int rmax) {
    int ob = t * 16;
    int e  = ob ^ (((ob >> 7) & 3) << 4);
    int m  = e >> 6, k = (e & 63) >> 1;
    int row = row0 + m; row = row < rmax ? row : rmax - 1;
    const unsigned short* gp = g + (long)row * ld + k0 + k;
    char* lp = lbuf + (t & ~63) * 16;  // wave-uniform; HW adds lane*16
    __builtin_amdgcn_global_load_lds((gas_t)(const void*)gp, (las_t)(void*)lp, 16, 0, 0);
  };
  // B tile [BN n x 32 k] from fp32 source B[k, n] (k-major): transpose + convert
  auto stageB_f32 = [&](char* lbuf, const float* g, int ld, int nb, int k0) {
    int ob = t * 16;
    int e  = ob ^ (((ob >> 7) & 3) << 4);
    int n  = e >> 6, kb = (e & 63) >> 1;
    bf16x8 pk;
    #pragma unroll
    for (int j = 0; j < 8; ++j) {
      float v = g[(long)(k0 + kb + j) * ld + nb + n];
      pk[j] = (short)f2bf(v);
    }
    *(bf16x8*)(lbuf + ob) = pk;
  };
  auto ldfrag = [&](const char* lbuf, int rr) -> bf16x8 {
    int ob = rr * 64 + (lane >> 4) * 16;
    ob ^= ((ob >> 7) & 3) << 4;
    return *(const bf16x8*)(lbuf + ob);
  };

  for (int k0 = 0; k0 < K; k0 += 32) {
    stage4k(As, Ab, ldA, m0, k0, M);
    if (BM == 128) stage4k(As + 4096, Ab, ldA, m0 + 64, k0, M);
    if (BF32) {
      stageB_f32(Bs, Bfb, ldB, n0, k0);
    } else {
      stage4k(Bs, Bb, ldB, n0, k0, N);
      if (BN == 128) stage4k(Bs + 4096, Bb, ldB, n0 + 64, k0, N);
    }
    if (SPLIT) {
      stage4k(Asl, Abl, ldA, m0, k0, M);
      if (BM == 128) stage4k(Asl + 4096, Abl, ldA, m0 + 64, k0, M);
      stage4k(Bsl, Bbl, ldB, n0, k0, N);
      if (BN == 128) stage4k(Bsl + 4096, Bbl, ldB, n0 + 64, k0, N);
    }
    __syncthreads();

    bf16x8 ah[MI], al[MI];
    #pragma unroll
    for (int mi = 0; mi < MI; ++mi) {
      int rr = wr * (BM / 2) + mi * 16 + (lane & 15);
      ah[mi] = ldfrag(As, rr);
      if (SPLIT) al[mi] = ldfrag(Asl, rr);
    }
    #pragma unroll
    for (int ni = 0; ni < NI; ++ni) {
      int rc = wc * (BN / 2) + ni * 16 + (lane & 15);
      bf16x8 bh = ldfrag(Bs, rc);
      bf16x8 bl;
      if (SPLIT) bl = ldfrag(Bsl, rc);
      #pragma unroll
      for (int mi = 0; mi < MI; ++mi) {
        acc[mi][ni] = __builtin_amdgcn_mfma_f32_16x16x32_bf16(ah[mi], bh, acc[mi][ni], 0, 0, 0);
        if (SPLIT) {
          acc[mi][ni] = __builtin_amdgcn_mfma_f32_16x16x32_bf16(ah[mi], bl, acc[mi][ni], 0, 0, 0);
          acc[mi][ni] = __builtin_amdgcn_mfma_f32_16x16x32_bf16(al[mi], bh, acc[mi][ni], 0, 0, 0);
        }
      }
    }
    __syncthreads();
  }

  if (OUT == 4 || OUT == 5) {
    float* red = (float*)smem;  // safe: k-loop ended with __syncthreads
    #pragma unroll
    for (int ni = 0; ni < NI; ++ni) {
      float pm = 0.0f;  // relu floor
      #pragma unroll
      for (int mi = 0; mi < MI; ++mi)
        #pragma unroll
        for (int r = 0; r < 4; ++r)
          pm = fmaxf(pm, acc[mi][ni][r]);
      int g = wr * 4 + (lane >> 4);
      int col = wc * (BN / 2) + ni * 16 + (lane & 15);
      red[g * BN + col] = pm;
    }
    __syncthreads();
    if (OUT == 4) {
      if (t < BN) {
        float m = red[t];
        #pragma unroll
        for (int g = 1; g < 8; ++g) m = fmaxf(m, red[g * BN + t]);
        Cf[(long)(z * mtiles + by) * ldC + n0 + t] = m;
      }
    } else {
      constexpr int NGR = BM / 64, PG = 8 / NGR;
      if (t < NGR * BN) {
        int hh = t / BN, col = t - hh * BN;
        float m = red[(hh * PG) * BN + col];
        #pragma unroll
        for (int i = 1; i < PG; ++i) m = fmaxf(m, red[(hh * PG + i) * BN + col]);
        Cf[(long)((m0 >> 6) + hh) * ldC + n0 + col] = m;
      }
    }
    return;
  }

  #pragma unroll
  for (int mi = 0; mi < MI; ++mi) {
    #pragma unroll
    for (int r = 0; r < 4; ++r) {
      int grow = m0 + wr * (BM / 2) + mi * 16 + (lane >> 4) * 4 + r;
      #pragma unroll
      for (int ni = 0; ni < NI; ++ni) {
        int gcol = n0 + wc * (BN / 2) + ni * 16 + (lane & 15);
        float v = acc[mi][ni][r];
        if (OUT == 1) {
          int b = grow >> 6, q = grow & 63;
          long dst = (long)b * 131072 + (long)((gcol >> 10) * 64 + q) * 1024 + (gcol & 1023);
          unsigned short h = f2bf(v);
          Ch[dst] = h;
          Cl[dst] = f2bf(v - bf2f(h));
        } else if (OUT == 2) {
          if (grow < M) Ch[(long)z * sC + (long)grow * ldC + gcol] = f2bf(v);
        } else if (OUT == 3) {
          long dst = (long)(grow >> 6) * 65536 + (long)gcol * 64 + (grow & 63);
          Ch[dst] = f2bf(v);
        }
      }
    }
  }
}

// ---------------- g1: Pcat (128x64) || P3T (64x64), 1024 blocks, natural order ----------------

__global__ __launch_bounds__(256) void g1_kernel(
    const unsigned short* Q_hi, const unsigned short* Q_lo,
    const unsigned short* Wcat_hi, const unsigned short* Wcat_lo,
    const unsigned short* W21T,
    unsigned short* Pcat_hi, unsigned short* Pcat_lo, unsigned short* P3T)
{
  __shared__ char smem[24576];
  int bid = blockIdx.x;  // natural: round-robin interleaves both work types across XCDs
  if (bid < 512) {   // Pcat: M=2048,N=2048,K=1024, tile 128x64, split
    gemm_body<128, 64, true, 1, false>(smem, bid & 31, bid >> 5, 0,
        Q_hi, Q_lo, Wcat_hi, Wcat_lo, nullptr, nullptr, Pcat_hi, Pcat_lo,
        2048, 2048, 1024, 1024, 1024, 0, 0, 0, 0, 0);
  } else {           // P3T: M=2048,N=1024,K=1024, tile 64x64
    int b2 = bid - 512;
    gemm_body<64, 64, false, 3, false>(smem, b2 & 15, b2 >> 4, 0,
        Q_hi, nullptr, W21T, nullptr, nullptr, nullptr, P3T, nullptr,
        2048, 1024, 1024, 1024, 1024, 0, 0, 0, 0, 0);
  }
}

// ---------------- g2: score partials, tile 64x128, 8 waves, K-split x2 ----------------

__global__ __launch_bounds__(512) void g2_kernel(
    const float* __restrict__ Afeat,
    const unsigned short* __restrict__ Pcat_hi, const unsigned short* __restrict__ Pcat_lo,
    float* __restrict__ Spar)
{
  __shared__ char smem[24576];
  char* Ash = smem;           // 4KB
  char* Asl = smem + 4096;    // 4KB
  char* Bs  = smem + 8192;    // 8KB
  char* Bsl = smem + 16384;   // 8KB

  int orig = blockIdx.x;            // 512 blocks; equal-cost, z-grouped for L2
  int xcd = orig & 7, idx = orig >> 3;
  int z   = xcd * 4 + (idx >> 4);   // 4 batches per XCD -> Pcat L2-resident
  int sub = idx & 15;
  int by  = sub >> 1, kh = sub & 1;
  const int m0 = by * 64, kb = kh * 512;
  const int t = threadIdx.x, lane = t & 63;
  const int wid = t >> 6, wr = wid >> 1, wc = wid & 1;

  const float* Ab = Afeat + (long)z * 524288;
  const unsigned short* Bbh = Pcat_hi + (long)z * 131072;
  const unsigned short* Bbl = Pcat_lo + (long)z * 131072;

  f32x4 acc[4];
  #pragma unroll
  for (int i = 0; i < 4; ++i) acc[i] = f32x4{0.f, 0.f, 0.f, 0.f};

  auto ldfrag = [&](const char* lbuf, int rr) -> bf16x8 {
    int ob = rr * 64 + (lane >> 4) * 16;
    ob ^= ((ob >> 7) & 3) << 4;
    return *(const bf16x8*)(lbuf + ob);
  };

  for (int k0 = kb; k0 < kb + 512; k0 += 32) {
    { // A: fp32 load + split + ds_write (8B hi + 8B lo per thread)
      int ob = t * 8;
      int e  = ob ^ (((ob >> 7) & 3) << 4);
      int m  = e >> 6, ke = (e & 63) >> 1;
      float4 v = *(const float4*)(Ab + (long)(m0 + m) * 1024 + k0 + ke);
      ushort4 h, l;
      h.x = f2bf(v.x); l.x = f2bf(v.x - bf2f(h.x));
      h.y = f2bf(v.y); l.y = f2bf(v.y - bf2f(h.y));
      h.z = f2bf(v.z); l.z = f2bf(v.z - bf2f(h.z));
      h.w = f2bf(v.w); l.w = f2bf(v.w - bf2f(h.w));
      *(ushort4*)(Ash + ob) = h;
      *(ushort4*)(Asl + ob) = l;
    }
    { // B: gload hi+lo, 8KB each (512 threads x 16B)
      int ob = t * 16;
      int e  = ob ^ (((ob >> 7) & 3) << 4);
      int n  = e >> 6, kk = (e & 63) >> 1;
      const unsigned short* gp  = Bbh + (long)n * 1024 + k0 + kk;
      const unsigned short* gpl = Bbl + (long)n * 1024 + k0 + kk;
      char* lp  = Bs  + (t & ~63) * 16;
      char* lpl = Bsl + (t & ~63) * 16;
      __builtin_amdgcn_global_load_lds((gas_t)(const void*)gp,  (las_t)(void*)lp,  16, 0, 0);
      __builtin_amdgcn_global_load_lds((gas_t)(const void*)gpl, (las_t)(void*)lpl, 16, 0, 0);
    }
    __syncthreads();

    bf16x8 ah  = ldfrag(Ash, wr * 16 + (lane & 15));
    bf16x8 alo = ldfrag(Asl, wr * 16 + (lane & 15));
    #pragma unroll
    for (int ni = 0; ni < 4; ++ni) {
      bf16x8 bh = ldfrag(Bs,  wc * 64 + ni * 16 + (lane & 15));
      bf16x8 bl = ldfrag(Bsl, wc * 64 + ni * 16 + (lane & 15));
      acc[ni] = __builtin_amdgcn_mfma_f32_16x16x32_bf16(ah,  bh, acc[ni], 0, 0, 0);
      acc[ni] = __builtin_amdgcn_mfma_f32_16x16x32_bf16(ah,  bl, acc[ni], 0, 0, 0);
      acc[ni] = __builtin_amdgcn_mfma_f32_16x16x32_bf16(alo, bh, acc[ni], 0, 0, 0);
    }
    __syncthreads();
  }

  // write fp32 partial scores
  float* dst = Spar + (long)kh * 2097152 + (long)z * 65536;
  #pragma unroll
  for (int r = 0; r < 4; ++r) {
    int grow = m0 + wr * 16 + (lane >> 4) * 4 + r;
    long base = (long)grow * 128 + wc * 64 + (lane & 15);
    dst[base]      = acc[0][r];
    dst[base + 16] = acc[1][r];
    dst[base + 32] = acc[2][r];
    dst[base + 48] = acc[3][r];
  }
}

// ---------------- softmaxes over partial sums ----------------

__global__ __launch_bounds__(256) void softmax_rows(const float* __restrict__ Sp,
                                                    unsigned short* __restrict__ aq)
{
  int row  = blockIdx.x * 4 + (threadIdx.x >> 6);
  int lane = threadIdx.x & 63;
  long o = (long)row * 128 + lane;
  float v = Sp[o] + Sp[o + 2097152];
  float m = v;
  #pragma unroll
  for (int off = 32; off; off >>= 1) m = fmaxf(m, __shfl_xor(m, off));
  float e = __expf(v - m);
  float s = e;
  #pragma unroll
  for (int off = 32; off; off >>= 1) s += __shfl_xor(s, off);
  aq[(long)row * 64 + lane] = f2bf(e / s);
}

__global__ __launch_bounds__(256) void softmax_cols(const float* __restrict__ Sp,
                                                    unsigned short* __restrict__ qa)
{
  int bq = blockIdx.x;
  int b = bq >> 6, q = bq & 63;
  int t = threadIdx.x;
  const float* base = Sp + (long)b * 65536 + 64 + q;
  float v0 = base[(long)t * 128]         + base[(long)t * 128 + 2097152];
  float v1 = base[(long)(t + 256) * 128] + base[(long)(t + 256) * 128 + 2097152];
  float m = fmaxf(v0, v1);
  #pragma unroll
  for (int off = 32; off; off >>= 1) m = fmaxf(m, __shfl_xor(m, off));
  __shared__ float sm[4], ss[4];
  int wid = t >> 6, lane = t & 63;
  if (lane == 0) sm[wid] = m;
  __syncthreads();
  float M = fmaxf(fmaxf(sm[0], sm[1]), fmaxf(sm[2], sm[3]));
  float e0 = __expf(v0 - M), e1 = __expf(v1 - M);
  float s = e0 + e1;
  #pragma unroll
  for (int off = 32; off; off >>= 1) s += __shfl_xor(s, off);
  if (lane == 0) ss[wid] = s;
  __syncthreads();
  float inv = 1.0f / ((ss[0] + ss[1]) + (ss[2] + ss[3]));
  qa[(long)bq * 512 + t]       = f2bf(e0 * inv);
  qa[(long)bq * 512 + t + 256] = f2bf(e1 * inv);
}

// ---------------- g3: PmaxA || ctx, 1536 blocks, natural order ----------------

__global__ __launch_bounds__(256) void g3_kernel(
    const unsigned short* aq, const unsigned short* P3T, float* PmaxA,
    const unsigned short* qa, const float* Afeat, unsigned short* ctx)
{
  __shared__ char smem[16384];
  int bid = blockIdx.x;  // natural order (heterogeneous work types)
  if (bid < 1024) {  // PmaxA: per batch M=512,N=1024,K=64, tile 128x128
    gemm_body<128, 128, false, 4, false>(smem, bid & 7, (bid >> 3) & 3, bid >> 5,
        aq, nullptr, P3T, nullptr, nullptr, PmaxA, nullptr, nullptr,
        512, 1024, 64, 64, 64, 1024, 32768L, 65536L, 0, 4);
  } else {           // ctx: per batch M=64,N=1024,K=512, tile 64x64, B = A fp32 (k-major)
    int b2 = bid - 1024;
    gemm_body<64, 64, false, 2, true>(smem, b2 & 15, 0, b2 >> 4,
        qa, nullptr, nullptr, nullptr, Afeat, nullptr, ctx, nullptr,
        64, 1024, 512, 512, 1024, 1024, 32768L, 524288L, 65536L, 0);
  }
}

// ---------------- g4 + final ----------------

__global__ __launch_bounds__(256) void g4_kernel(
    const unsigned short* ctx, const unsigned short* W22T, float* PmaxQ)
{
  __shared__ char smem[8192];
  gemm_body<64, 64, false, 5, false>(smem, blockIdx.x, blockIdx.y, 0,
      ctx, nullptr, W22T, nullptr, nullptr, PmaxQ, nullptr, nullptr,
      2048, 1024, 1024, 1024, 1024, 1024, 0, 0, 0, 0);
}

__global__ __launch_bounds__(256) void final_combine(
    const float* __restrict__ PmaxA, const float* __restrict__ PmaxQ, float* __restrict__ out)
{
  int idx = blockIdx.x * 256 + threadIdx.x;  // 32768
  int b = idx >> 10, h = idx & 1023;
  float m = PmaxA[(long)(b * 4) * 1024 + h];
  #pragma unroll
  for (int mt = 1; mt < 4; ++mt)
    m = fmaxf(m, PmaxA[(long)(b * 4 + mt) * 1024 + h]);
  out[idx] = 0.5f * m + 0.5f * PmaxQ[idx];
}

// ---------------- launch ----------------

extern "C" void kernel_launch(void* const* d_in, const int* in_sizes, int n_in,
                              void* d_out, int out_size, void* d_ws, size_t ws_size,
                              hipStream_t stream) {
  const float* Afeat = (const float*)d_in[0];
  const float* Qfeat = (const float*)d_in[1];
  const float* W11   = (const float*)d_in[2];
  const float* W12   = (const float*)d_in[3];
  const float* W21   = (const float*)d_in[4];
  const float* W22   = (const float*)d_in[5];
  float* out = (float*)d_out;

  char* w = (char*)d_ws;
  auto alloc = [&](long bytes) { char* p = w; w += bytes; return p; };
  unsigned short* Q_hi    = (unsigned short*)alloc(4194304);
  unsigned short* Q_lo    = (unsigned short*)alloc(4194304);
  unsigned short* Wcat_hi = (unsigned short*)alloc(4194304);   // [2048][1024]
  unsigned short* Wcat_lo = (unsigned short*)alloc(4194304);
  unsigned short* W21T    = (unsigned short*)alloc(2097152);
  unsigned short* W22T    = (unsigned short*)alloc(2097152);
  unsigned short* Pcat_hi = (unsigned short*)alloc(8388608);   // [32][128][1024]
  unsigned short* Pcat_lo = (unsigned short*)alloc(8388608);
  unsigned short* P3T     = (unsigned short*)alloc(4194304);   // [32][1024][64]
  float*          Spar    = (float*)alloc(16777216);           // [2][32][512][128]
  unsigned short* aq      = (unsigned short*)alloc(2097152);   // [32][512][64]
  unsigned short* qa      = (unsigned short*)alloc(2097152);   // [32][64][512]
  unsigned short* ctx     = (unsigned short*)alloc(4194304);   // [32][64][1024]
  float*          PmaxA   = (float*)alloc(524288);             // [128][1024]
  float*          PmaxQ   = (float*)alloc(131072);             // [32][1024]

  dim3 blk(256), tblk(32, 8);

  conv_split<<<2048, blk, 0, stream>>>(Qfeat, Q_hi, Q_lo, 524288);
  prep_W<<<dim3(32, 32, 4), tblk, 0, stream>>>(W11, W12, W21, W22, Wcat_hi, Wcat_lo, W21T, W22T);

  g1_kernel<<<1024, blk, 0, stream>>>(Q_hi, Q_lo, Wcat_hi, Wcat_lo, W21T, Pcat_hi, Pcat_lo, P3T);
  g2_kernel<<<512, dim3(512), 0, stream>>>(Afeat, Pcat_hi, Pcat_lo, Spar);
  softmax_rows<<<4096, blk, 0, stream>>>(Spar, aq);
  softmax_cols<<<2048, blk, 0, stream>>>(Spar, qa);
  g3_kernel<<<1536, blk, 0, stream>>>(aq, P3T, PmaxA, qa, Afeat, ctx);
  g4_kernel<<<dim3(16, 32), blk, 0, stream>>>(ctx, W22T, PmaxQ);
  final_combine<<<128, blk, 0, stream>>>(PmaxA, PmaxQ, out);
}

// Round 8
// 128.875 us; speedup vs baseline: 1.5283x; 1.1088x over previous
//
#include <hip/hip_runtime.h>
#include <stdint.h>

// B=32, La=512, Lq=64, H=1024. ALL-FP16 pipeline.
// Score path: asymmetric 2-MFMA split (fp16 truncation err 2^-11 -> score err ~0.005/operand):
//   Pcat = Q(hi+lo fp16) @ Wcat(hi fp16)^T      [only W trunc leaks]
//   scores = A(hi fp16) @ Pcat(hi+lo fp16)^T    [only A trunc leaks]
// Value path: plain fp16 single MFMA (better than bf16 was).
// g1: Pcat (128x64, ASPL, remap) || P3T = (Q@W21)^T        [1024 blocks, natural order]
// g2: score partials, K-split x2                            [512 blocks]
// softmax_both: aq = rowsoftmax(Sp0+Sp1), qa = colsoftmax
// g3: PmaxA = colmax(relu(aq@P3T^T)) || ctx = qa@A (A fp32 staged->fp16)
// g4: PmaxQ = colmax64(relu(ctx@W22T^T));  final: 0.5*max4(PmaxA)+0.5*PmaxQ

using f16x8 = __attribute__((ext_vector_type(8))) _Float16;
using f32x4 = __attribute__((ext_vector_type(4))) float;
typedef const __attribute__((address_space(1))) void* gas_t;
typedef __attribute__((address_space(3))) void* las_t;

__device__ __forceinline__ unsigned short f2h(float x) {
  _Float16 h = (_Float16)x;
  return __builtin_bit_cast(unsigned short, h);
}
__device__ __forceinline__ float h2f(unsigned short u) {
  return (float)__builtin_bit_cast(_Float16, u);
}

// ---------------- prep ----------------

__global__ __launch_bounds__(256) void conv_split(const float* __restrict__ in,
    unsigned short* __restrict__ hi, unsigned short* __restrict__ lo)
{
  int i = blockIdx.x * 256 + threadIdx.x;  // 524288 float4 groups
  float4 v = ((const float4*)in)[i];
  ushort4 h, l;
  h.x = f2h(v.x); l.x = f2h(v.x - h2f(h.x));
  h.y = f2h(v.y); l.y = f2h(v.y - h2f(h.y));
  h.z = f2h(v.z); l.z = f2h(v.z - h2f(h.z));
  h.w = f2h(v.w); l.w = f2h(v.w - h2f(h.w));
  ((ushort4*)hi)[i] = h;
  ((ushort4*)lo)[i] = l;
}

// z=0: W11 straight; z=1: W12 transpose; z=2: W21T; z=3: W22T (all fp16 hi only)
__global__ __launch_bounds__(256) void prep_W(
    const float* __restrict__ W11, const float* __restrict__ W12,
    const float* __restrict__ W21, const float* __restrict__ W22,
    unsigned short* __restrict__ Wcat, unsigned short* __restrict__ W21T,
    unsigned short* __restrict__ W22T)
{
  __shared__ float tile[32][33];
  int z = blockIdx.z;
  const float* src = z == 0 ? W11 : z == 1 ? W12 : z == 2 ? W21 : W22;
  int r0 = blockIdx.y * 32, c0 = blockIdx.x * 32;
  int tx = threadIdx.x, ty = threadIdx.y;
  #pragma unroll
  for (int i = 0; i < 4; ++i) {
    int r = r0 + ty + i * 8;
    float v = src[(long)r * 1024 + c0 + tx];
    tile[ty + i * 8][tx] = v;
    if (z == 0) Wcat[(long)r * 1024 + c0 + tx] = f2h(v);
  }
  __syncthreads();
  if (z > 0) {
    #pragma unroll
    for (int i = 0; i < 4; ++i) {
      float v = tile[tx][ty + i * 8];
      long o = (long)(c0 + ty + i * 8) * 1024 + r0 + tx;
      if (z == 1)      Wcat[1048576 + o] = f2h(v);
      else if (z == 2) W21T[o] = f2h(v);
      else             W22T[o] = f2h(v);
    }
  }
}

// ---------------- generic MFMA GEMM body (C = A @ B^T), single-buffered, fp16 ----------------
// ASPL: A operand split (hi+lo), B hi only -> 2 MFMA/pair.
// OUT: 1=Pcat split remap, 2=fp16 (row<M), 3=P3T transpose, 4=relu+colmax(BM),
// 5=relu+colmax per 64 rows. BF32: B operand fp32 [K x ldB] k-major, staged->fp16.
template<int BM, int BN, bool ASPL, int OUT, bool BF32>
__device__ __forceinline__ void gemm_body(
    char* smem, int bx, int by, int z,
    const unsigned short* __restrict__ Ah, const unsigned short* __restrict__ Al,
    const unsigned short* __restrict__ Bh, const float* __restrict__ Bf,
    float* __restrict__ Cf, unsigned short* __restrict__ Ch, unsigned short* __restrict__ Cl,
    int M, int N, int K, int ldA, int ldB, int ldC, long sA, long sB, long sC, int mtiles)
{
  constexpr int AB = BM * 64;
  constexpr int MI = BM / 32, NI = BN / 32;
  char* As  = smem;
  char* Asl = ASPL ? smem + AB : nullptr;
  char* Bs  = smem + (ASPL ? 2 * AB : AB);

  const int m0 = by * BM, n0 = bx * BN;
  const int t = threadIdx.x, lane = t & 63;
  const int wid = t >> 6, wr = wid >> 1, wc = wid & 1;

  const unsigned short* Ab  = Ah + (long)z * sA;
  const unsigned short* Abl = ASPL ? Al + (long)z * sA : nullptr;
  const unsigned short* Bb  = BF32 ? nullptr : Bh + (long)z * sB;
  const float* Bfb = BF32 ? Bf + (long)z * sB : nullptr;

  f32x4 acc[MI][NI];
  #pragma unroll
  for (int i = 0; i < MI; ++i)
    #pragma unroll
    for (int j = 0; j < NI; ++j)
      acc[i][j] = f32x4{0.f, 0.f, 0.f, 0.f};

  auto stage4k = [&](char* lbuf, const unsigned short* g, int ld, int row0, int k0, int rmax) {
    int ob = t * 16;
    int e  = ob ^ (((ob >> 7) & 3) << 4);
    int m  = e >> 6, k = (e & 63) >> 1;
    int row = row0 + m; row = row < rmax ? row : rmax - 1;
    const unsigned short* gp = g + (long)row * ld + k0 + k;
    char* lp = lbuf + (t & ~63) * 16;  // wave-uniform; HW adds lane*16
    __builtin_amdgcn_global_load_lds((gas_t)(const void*)gp, (las_t)(void*)lp, 16, 0, 0);
  };
  // B tile [BN n x 32 k] from fp32 source B[k, n] (k-major): transpose + convert
  auto stageB_f32 = [&](char* lbuf, const float* g, int ld, int nb, int k0) {
    int ob = t * 16;
    int e  = ob ^ (((ob >> 7) & 3) << 4);
    int n  = e >> 6, kb = (e & 63) >> 1;
    f16x8 pk;
    #pragma unroll
    for (int j = 0; j < 8; ++j) {
      float v = g[(long)(k0 + kb + j) * ld + nb + n];
      pk[j] = (_Float16)v;
    }
    *(f16x8*)(lbuf + ob) = pk;
  };
  auto ldfrag = [&](const char* lbuf, int rr) -> f16x8 {
    int ob = rr * 64 + (lane >> 4) * 16;
    ob ^= ((ob >> 7) & 3) << 4;
    return *(const f16x8*)(lbuf + ob);
  };

  for (int k0 = 0; k0 < K; k0 += 32) {
    stage4k(As, Ab, ldA, m0, k0, M);
    if (BM == 128) stage4k(As + 4096, Ab, ldA, m0 + 64, k0, M);
    if (ASPL) {
      stage4k(Asl, Abl, ldA, m0, k0, M);
      if (BM == 128) stage4k(Asl + 4096, Abl, ldA, m0 + 64, k0, M);
    }
    if (BF32) {
      stageB_f32(Bs, Bfb, ldB, n0, k0);
    } else {
      stage4k(Bs, Bb, ldB, n0, k0, N);
      if (BN == 128) stage4k(Bs + 4096, Bb, ldB, n0 + 64, k0, N);
    }
    __syncthreads();

    f16x8 ah[MI], al[MI];
    #pragma unroll
    for (int mi = 0; mi < MI; ++mi) {
      int rr = wr * (BM / 2) + mi * 16 + (lane & 15);
      ah[mi] = ldfrag(As, rr);
      if (ASPL) al[mi] = ldfrag(Asl, rr);
    }
    #pragma unroll
    for (int ni = 0; ni < NI; ++ni) {
      int rc = wc * (BN / 2) + ni * 16 + (lane & 15);
      f16x8 bh = ldfrag(Bs, rc);
      #pragma unroll
      for (int mi = 0; mi < MI; ++mi) {
        acc[mi][ni] = __builtin_amdgcn_mfma_f32_16x16x32_f16(ah[mi], bh, acc[mi][ni], 0, 0, 0);
        if (ASPL)
          acc[mi][ni] = __builtin_amdgcn_mfma_f32_16x16x32_f16(al[mi], bh, acc[mi][ni], 0, 0, 0);
      }
    }
    __syncthreads();
  }

  if (OUT == 4 || OUT == 5) {
    float* red = (float*)smem;  // safe: k-loop ended with __syncthreads
    #pragma unroll
    for (int ni = 0; ni < NI; ++ni) {
      float pm = 0.0f;  // relu floor
      #pragma unroll
      for (int mi = 0; mi < MI; ++mi)
        #pragma unroll
        for (int r = 0; r < 4; ++r)
          pm = fmaxf(pm, acc[mi][ni][r]);
      int g = wr * 4 + (lane >> 4);
      int col = wc * (BN / 2) + ni * 16 + (lane & 15);
      red[g * BN + col] = pm;
    }
    __syncthreads();
    if (OUT == 4) {
      if (t < BN) {
        float m = red[t];
        #pragma unroll
        for (int g = 1; g < 8; ++g) m = fmaxf(m, red[g * BN + t]);
        Cf[(long)(z * mtiles + by) * ldC + n0 + t] = m;
      }
    } else {
      constexpr int NGR = BM / 64, PG = 8 / NGR;
      if (t < NGR * BN) {
        int hh = t / BN, col = t - hh * BN;
        float m = red[(hh * PG) * BN + col];
        #pragma unroll
        for (int i = 1; i < PG; ++i) m = fmaxf(m, red[(hh * PG + i) * BN + col]);
        Cf[(long)((m0 >> 6) + hh) * ldC + n0 + col] = m;
      }
    }
    return;
  }

  #pragma unroll
  for (int mi = 0; mi < MI; ++mi) {
    #pragma unroll
    for (int r = 0; r < 4; ++r) {
      int grow = m0 + wr * (BM / 2) + mi * 16 + (lane >> 4) * 4 + r;
      #pragma unroll
      for (int ni = 0; ni < NI; ++ni) {
        int gcol = n0 + wc * (BN / 2) + ni * 16 + (lane & 15);
        float v = acc[mi][ni][r];
        if (OUT == 1) {
          int b = grow >> 6, q = grow & 63;
          long dst = (long)b * 131072 + (long)((gcol >> 10) * 64 + q) * 1024 + (gcol & 1023);
          unsigned short h = f2h(v);
          Ch[dst] = h;
          Cl[dst] = f2h(v - h2f(h));
        } else if (OUT == 2) {
          if (grow < M) Ch[(long)z * sC + (long)grow * ldC + gcol] = f2h(v);
        } else if (OUT == 3) {
          long dst = (long)(grow >> 6) * 65536 + (long)gcol * 64 + (grow & 63);
          Ch[dst] = f2h(v);
        }
      }
    }
  }
}

// ---------------- g1: Pcat (128x64, ASPL) || P3T (64x64), natural order ----------------

__global__ __launch_bounds__(256) void g1_kernel(
    const unsigned short* Q_hi, const unsigned short* Q_lo,
    const unsigned short* Wcat, const unsigned short* W21T,
    unsigned short* Pcat_hi, unsigned short* Pcat_lo, unsigned short* P3T)
{
  __shared__ char smem[20480];
  int bid = blockIdx.x;  // natural: round-robin interleaves work types across XCDs
  if (bid < 512) {   // Pcat: M=2048,N=2048,K=1024, tile 128x64, A-split
    gemm_body<128, 64, true, 1, false>(smem, bid & 31, bid >> 5, 0,
        Q_hi, Q_lo, Wcat, nullptr, nullptr, Pcat_hi, Pcat_lo,
        2048, 2048, 1024, 1024, 1024, 0, 0, 0, 0, 0);
  } else {           // P3T: M=2048,N=1024,K=1024, tile 64x64
    int b2 = bid - 512;
    gemm_body<64, 64, false, 3, false>(smem, b2 & 15, b2 >> 4, 0,
        Q_hi, nullptr, W21T, nullptr, nullptr, P3T, nullptr,
        2048, 1024, 1024, 1024, 1024, 0, 0, 0, 0, 0);
  }
}

// ---------------- g2: score partials = A(hi)@Pcat(hi+lo)^T, K-split x2 ----------------

__global__ __launch_bounds__(512) void g2_kernel(
    const float* __restrict__ Afeat,
    const unsigned short* __restrict__ Pcat_hi, const unsigned short* __restrict__ Pcat_lo,
    float* __restrict__ Spar)
{
  __shared__ char smem[20480];
  char* Ash = smem;           // 4KB (hi only)
  char* Bs  = smem + 4096;    // 8KB
  char* Bsl = smem + 12288;   // 8KB

  int orig = blockIdx.x;            // 512 blocks; z-grouped for L2
  int xcd = orig & 7, idx = orig >> 3;
  int z   = xcd * 4 + (idx >> 4);   // 4 batches per XCD -> Pcat L2-resident
  int sub = idx & 15;
  int by  = sub >> 1, kh = sub & 1;
  const int m0 = by * 64, kb = kh * 512;
  const int t = threadIdx.x, lane = t & 63;
  const int wid = t >> 6, wr = wid >> 1, wc = wid & 1;

  const float* Ab = Afeat + (long)z * 524288;
  const unsigned short* Bbh = Pcat_hi + (long)z * 131072;
  const unsigned short* Bbl = Pcat_lo + (long)z * 131072;

  f32x4 acc[4];
  #pragma unroll
  for (int i = 0; i < 4; ++i) acc[i] = f32x4{0.f, 0.f, 0.f, 0.f};

  auto ldfrag = [&](const char* lbuf, int rr) -> f16x8 {
    int ob = rr * 64 + (lane >> 4) * 16;
    ob ^= ((ob >> 7) & 3) << 4;
    return *(const f16x8*)(lbuf + ob);
  };

  for (int k0 = kb; k0 < kb + 512; k0 += 32) {
    { // A: fp32 load + fp16 hi convert + 8B ds_write (512 thr cover 64 rows x 32 k)
      int ob = t * 8;
      int e  = ob ^ (((ob >> 7) & 3) << 4);
      int m  = e >> 6, ke = (e & 63) >> 1;
      float4 v = *(const float4*)(Ab + (long)(m0 + m) * 1024 + k0 + ke);
      ushort4 h;
      h.x = f2h(v.x); h.y = f2h(v.y); h.z = f2h(v.z); h.w = f2h(v.w);
      *(ushort4*)(Ash + ob) = h;
    }
    { // B: gload hi+lo, 8KB each
      int ob = t * 16;
      int e  = ob ^ (((ob >> 7) & 3) << 4);
      int n  = e >> 6, kk = (e & 63) >> 1;
      const unsigned short* gp  = Bbh + (long)n * 1024 + k0 + kk;
      const unsigned short* gpl = Bbl + (long)n * 1024 + k0 + kk;
      char* lp  = Bs  + (t & ~63) * 16;
      char* lpl = Bsl + (t & ~63) * 16;
      __builtin_amdgcn_global_load_lds((gas_t)(const void*)gp,  (las_t)(void*)lp,  16, 0, 0);
      __builtin_amdgcn_global_load_lds((gas_t)(const void*)gpl, (las_t)(void*)lpl, 16, 0, 0);
    }
    __syncthreads();

    f16x8 ah = ldfrag(Ash, wr * 16 + (lane & 15));
    #pragma unroll
    for (int ni = 0; ni < 4; ++ni) {
      f16x8 bh = ldfrag(Bs,  wc * 64 + ni * 16 + (lane & 15));
      f16x8 bl = ldfrag(Bsl, wc * 64 + ni * 16 + (lane & 15));
      acc[ni] = __builtin_amdgcn_mfma_f32_16x16x32_f16(ah, bh, acc[ni], 0, 0, 0);
      acc[ni] = __builtin_amdgcn_mfma_f32_16x16x32_f16(ah, bl, acc[ni], 0, 0, 0);
    }
    __syncthreads();
  }

  // write fp32 partial scores
  float* dst = Spar + (long)kh * 2097152 + (long)z * 65536;
  #pragma unroll
  for (int r = 0; r < 4; ++r) {
    int grow = m0 + wr * 16 + (lane >> 4) * 4 + r;
    long base = (long)grow * 128 + wc * 64 + (lane & 15);
    dst[base]      = acc[0][r];
    dst[base + 16] = acc[1][r];
    dst[base + 32] = acc[2][r];
    dst[base + 48] = acc[3][r];
  }
}

// ---------------- merged softmaxes over partial sums ----------------

__global__ __launch_bounds__(256) void softmax_both(const float* __restrict__ Sp,
    unsigned short* __restrict__ aq, unsigned short* __restrict__ qa)
{
  if (blockIdx.x < 4096) {
    int row  = blockIdx.x * 4 + (threadIdx.x >> 6);
    int lane = threadIdx.x & 63;
    long o = (long)row * 128 + lane;
    float v = Sp[o] + Sp[o + 2097152];
    float m = v;
    #pragma unroll
    for (int off = 32; off; off >>= 1) m = fmaxf(m, __shfl_xor(m, off));
    float e = __expf(v - m);
    float s = e;
    #pragma unroll
    for (int off = 32; off; off >>= 1) s += __shfl_xor(s, off);
    aq[(long)row * 64 + lane] = f2h(e / s);
  } else {
    int bq = blockIdx.x - 4096;
    int b = bq >> 6, q = bq & 63;
    int t = threadIdx.x;
    const float* base = Sp + (long)b * 65536 + 64 + q;
    float v0 = base[(long)t * 128]         + base[(long)t * 128 + 2097152];
    float v1 = base[(long)(t + 256) * 128] + base[(long)(t + 256) * 128 + 2097152];
    float m = fmaxf(v0, v1);
    #pragma unroll
    for (int off = 32; off; off >>= 1) m = fmaxf(m, __shfl_xor(m, off));
    __shared__ float sm[4], ss[4];
    int wid = t >> 6, lane = t & 63;
    if (lane == 0) sm[wid] = m;
    __syncthreads();
    float M = fmaxf(fmaxf(sm[0], sm[1]), fmaxf(sm[2], sm[3]));
    float e0 = __expf(v0 - M), e1 = __expf(v1 - M);
    float s = e0 + e1;
    #pragma unroll
    for (int off = 32; off; off >>= 1) s += __shfl_xor(s, off);
    if (lane == 0) ss[wid] = s;
    __syncthreads();
    float inv = 1.0f / ((ss[0] + ss[1]) + (ss[2] + ss[3]));
    qa[(long)bq * 512 + t]       = f2h(e0 * inv);
    qa[(long)bq * 512 + t + 256] = f2h(e1 * inv);
  }
}

// ---------------- g3: PmaxA || ctx, natural order ----------------

__global__ __launch_bounds__(256) void g3_kernel(
    const unsigned short* aq, const unsigned short* P3T, float* PmaxA,
    const unsigned short* qa, const float* Afeat, unsigned short* ctx)
{
  __shared__ char smem[16384];
  int bid = blockIdx.x;  // natural order (heterogeneous work types)
  if (bid < 1024) {  // PmaxA: per batch M=512,N=1024,K=64, tile 128x128
    gemm_body<128, 128, false, 4, false>(smem, bid & 7, (bid >> 3) & 3, bid >> 5,
        aq, nullptr, P3T, nullptr, PmaxA, nullptr, nullptr,
        512, 1024, 64, 64, 64, 1024, 32768L, 65536L, 0, 4);
  } else {           // ctx: per batch M=64,N=1024,K=512, tile 64x64, B = A fp32 (k-major)
    int b2 = bid - 1024;
    gemm_body<64, 64, false, 2, true>(smem, b2 & 15, 0, b2 >> 4,
        qa, nullptr, nullptr, Afeat, nullptr, ctx, nullptr,
        64, 1024, 512, 512, 1024, 1024, 32768L, 524288L, 65536L, 0);
  }
}

// ---------------- g4 + final ----------------

__global__ __launch_bounds__(256) void g4_kernel(
    const unsigned short* ctx, const unsigned short* W22T, float* PmaxQ)
{
  __shared__ char smem[8192];
  gemm_body<64, 64, false, 5, false>(smem, blockIdx.x, blockIdx.y, 0,
      ctx, nullptr, W22T, nullptr, PmaxQ, nullptr, nullptr,
      2048, 1024, 1024, 1024, 1024, 1024, 0, 0, 0, 0);
}

__global__ __launch_bounds__(256) void final_combine(
    const float* __restrict__ PmaxA, const float* __restrict__ PmaxQ, float* __restrict__ out)
{
  int idx = blockIdx.x * 256 + threadIdx.x;  // 32768
  int b = idx >> 10, h = idx & 1023;
  float m = PmaxA[(long)(b * 4) * 1024 + h];
  #pragma unroll
  for (int mt = 1; mt < 4; ++mt)
    m = fmaxf(m, PmaxA[(long)(b * 4 + mt) * 1024 + h]);
  out[idx] = 0.5f * m + 0.5f * PmaxQ[idx];
}

// ---------------- launch ----------------

extern "C" void kernel_launch(void* const* d_in, const int* in_sizes, int n_in,
                              void* d_out, int out_size, void* d_ws, size_t ws_size,
                              hipStream_t stream) {
  const float* Afeat = (const float*)d_in[0];
  const float* Qfeat = (const float*)d_in[1];
  const float* W11   = (const float*)d_in[2];
  const float* W12   = (const float*)d_in[3];
  const float* W21   = (const float*)d_in[4];
  const float* W22   = (const float*)d_in[5];
  float* out = (float*)d_out;

  char* w = (char*)d_ws;
  auto alloc = [&](long bytes) { char* p = w; w += bytes; return p; };
  unsigned short* Q_hi    = (unsigned short*)alloc(4194304);
  unsigned short* Q_lo    = (unsigned short*)alloc(4194304);
  unsigned short* Wcat    = (unsigned short*)alloc(4194304);   // [2048][1024] fp16: W11 ; W12^T
  unsigned short* W21T    = (unsigned short*)alloc(2097152);
  unsigned short* W22T    = (unsigned short*)alloc(2097152);
  unsigned short* Pcat_hi = (unsigned short*)alloc(8388608);   // [32][128][1024]
  unsigned short* Pcat_lo = (unsigned short*)alloc(8388608);
  unsigned short* P3T     = (unsigned short*)alloc(4194304);   // [32][1024][64]
  float*          Spar    = (float*)alloc(16777216);           // [2][32][512][128]
  unsigned short* aq      = (unsigned short*)alloc(2097152);   // [32][512][64]
  unsigned short* qa      = (unsigned short*)alloc(2097152);   // [32][64][512]
  unsigned short* ctx     = (unsigned short*)alloc(4194304);   // [32][64][1024]
  float*          PmaxA   = (float*)alloc(524288);             // [128][1024]
  float*          PmaxQ   = (float*)alloc(131072);             // [32][1024]

  dim3 blk(256), tblk(32, 8);

  conv_split<<<2048, blk, 0, stream>>>(Qfeat, Q_hi, Q_lo);
  prep_W<<<dim3(32, 32, 4), tblk, 0, stream>>>(W11, W12, W21, W22, Wcat, W21T, W22T);

  g1_kernel<<<1024, blk, 0, stream>>>(Q_hi, Q_lo, Wcat, W21T, Pcat_hi, Pcat_lo, P3T);
  g2_kernel<<<512, dim3(512), 0, stream>>>(Afeat, Pcat_hi, Pcat_lo, Spar);
  softmax_both<<<6144, blk, 0, stream>>>(Spar, aq, qa);
  g3_kernel<<<1536, blk, 0, stream>>>(aq, P3T, PmaxA, qa, Afeat, ctx);
  g4_kernel<<<dim3(16, 32), blk, 0, stream>>>(ctx, W22T, PmaxQ);
  final_combine<<<128, blk, 0, stream>>>(PmaxA, PmaxQ, out);
}

// Round 9
// 110.365 us; speedup vs baseline: 1.7847x; 1.1677x over previous
//
#include <hip/hip_runtime.h>
#include <stdint.h>

// B=32, La=512, Lq=64, H=1024. PLAIN-FP16 pipeline (error budget verified R8:
// two fp16 truncations -> absmax 0.0078; four -> predicted ~0.012..0.016 vs thr 0.0456).
// g1: Pcat = Q@Wcat^T (128x64, remap) || P3T = (Q@W21)^T (128x64)  [768 blocks, natural]
// g2: score partials = A(fp32 reg-staged)@Pcat^T, K-split x2        [512 blocks]
// softmax_both: aq = rowsoftmax(Sp0+Sp1), qa = colsoftmax (fp16 out)
// g3: PmaxA = colmax(relu(aq@P3T^T)) || ctx = qa@A (A fp32 staged->fp16)
// g4: PmaxQ = colmax64(relu(ctx@W22T^T));  final: 0.5*max4(PmaxA)+0.5*PmaxQ

using f16x8 = __attribute__((ext_vector_type(8))) _Float16;
using f32x4 = __attribute__((ext_vector_type(4))) float;
typedef const __attribute__((address_space(1))) void* gas_t;
typedef __attribute__((address_space(3))) void* las_t;

__device__ __forceinline__ unsigned short f2h(float x) {
  _Float16 h = (_Float16)x;
  return __builtin_bit_cast(unsigned short, h);
}

// ---------------- prep ----------------

__global__ __launch_bounds__(256) void conv16(const float* __restrict__ in,
    unsigned short* __restrict__ hi)
{
  int i = blockIdx.x * 256 + threadIdx.x;  // 524288 float4 groups for Q
  float4 v = ((const float4*)in)[i];
  ushort4 h;
  h.x = f2h(v.x); h.y = f2h(v.y); h.z = f2h(v.z); h.w = f2h(v.w);
  ((ushort4*)hi)[i] = h;
}

// z=0: W11 straight; z=1: W12 transpose; z=2: W21T; z=3: W22T (fp16)
__global__ __launch_bounds__(256) void prep_W(
    const float* __restrict__ W11, const float* __restrict__ W12,
    const float* __restrict__ W21, const float* __restrict__ W22,
    unsigned short* __restrict__ Wcat, unsigned short* __restrict__ W21T,
    unsigned short* __restrict__ W22T)
{
  __shared__ float tile[32][33];
  int z = blockIdx.z;
  const float* src = z == 0 ? W11 : z == 1 ? W12 : z == 2 ? W21 : W22;
  int r0 = blockIdx.y * 32, c0 = blockIdx.x * 32;
  int tx = threadIdx.x, ty = threadIdx.y;
  #pragma unroll
  for (int i = 0; i < 4; ++i) {
    int r = r0 + ty + i * 8;
    float v = src[(long)r * 1024 + c0 + tx];
    tile[ty + i * 8][tx] = v;
    if (z == 0) Wcat[(long)r * 1024 + c0 + tx] = f2h(v);
  }
  __syncthreads();
  if (z > 0) {
    #pragma unroll
    for (int i = 0; i < 4; ++i) {
      float v = tile[tx][ty + i * 8];
      long o = (long)(c0 + ty + i * 8) * 1024 + r0 + tx;
      if (z == 1)      Wcat[1048576 + o] = f2h(v);
      else if (z == 2) W21T[o] = f2h(v);
      else             W22T[o] = f2h(v);
    }
  }
}

// ---------------- generic MFMA GEMM body (C = A @ B^T), single-buffered, fp16 ----------------
// OUT: 1=Pcat remap, 2=fp16 (row<M), 3=transpose remap, 4=relu+colmax(BM),
// 5=relu+colmax per 64 rows. BF32: B operand fp32 [K x ldB] k-major, staged->fp16.
template<int BM, int BN, int OUT, bool BF32>
__device__ __forceinline__ void gemm_body(
    char* smem, int bx, int by, int z,
    const unsigned short* __restrict__ Ah,
    const unsigned short* __restrict__ Bh, const float* __restrict__ Bf,
    float* __restrict__ Cf, unsigned short* __restrict__ Ch,
    int M, int N, int K, int ldA, int ldB, int ldC, long sA, long sB, long sC, int mtiles)
{
  constexpr int AB = BM * 64;
  constexpr int MI = BM / 32, NI = BN / 32;
  char* As = smem;
  char* Bs = smem + AB;

  const int m0 = by * BM, n0 = bx * BN;
  const int t = threadIdx.x, lane = t & 63;
  const int wid = t >> 6, wr = wid >> 1, wc = wid & 1;

  const unsigned short* Ab = Ah + (long)z * sA;
  const unsigned short* Bb = BF32 ? nullptr : Bh + (long)z * sB;
  const float* Bfb = BF32 ? Bf + (long)z * sB : nullptr;

  f32x4 acc[MI][NI];
  #pragma unroll
  for (int i = 0; i < MI; ++i)
    #pragma unroll
    for (int j = 0; j < NI; ++j)
      acc[i][j] = f32x4{0.f, 0.f, 0.f, 0.f};

  auto stage4k = [&](char* lbuf, const unsigned short* g, int ld, int row0, int k0, int rmax) {
    int ob = t * 16;
    int e  = ob ^ (((ob >> 7) & 3) << 4);
    int m  = e >> 6, k = (e & 63) >> 1;
    int row = row0 + m; row = row < rmax ? row : rmax - 1;
    const unsigned short* gp = g + (long)row * ld + k0 + k;
    char* lp = lbuf + (t & ~63) * 16;  // wave-uniform; HW adds lane*16
    __builtin_amdgcn_global_load_lds((gas_t)(const void*)gp, (las_t)(void*)lp, 16, 0, 0);
  };
  // B tile [BN n x 32 k] from fp32 source B[k, n] (k-major): transpose + convert
  auto stageB_f32 = [&](char* lbuf, const float* g, int ld, int nb, int k0) {
    int ob = t * 16;
    int e  = ob ^ (((ob >> 7) & 3) << 4);
    int n  = e >> 6, kb = (e & 63) >> 1;
    f16x8 pk;
    #pragma unroll
    for (int j = 0; j < 8; ++j) {
      float v = g[(long)(k0 + kb + j) * ld + nb + n];
      pk[j] = (_Float16)v;
    }
    *(f16x8*)(lbuf + ob) = pk;
  };
  auto ldfrag = [&](const char* lbuf, int rr) -> f16x8 {
    int ob = rr * 64 + (lane >> 4) * 16;
    ob ^= ((ob >> 7) & 3) << 4;
    return *(const f16x8*)(lbuf + ob);
  };

  for (int k0 = 0; k0 < K; k0 += 32) {
    stage4k(As, Ab, ldA, m0, k0, M);
    if (BM == 128) stage4k(As + 4096, Ab, ldA, m0 + 64, k0, M);
    if (BF32) {
      stageB_f32(Bs, Bfb, ldB, n0, k0);
    } else {
      stage4k(Bs, Bb, ldB, n0, k0, N);
      if (BN == 128) stage4k(Bs + 4096, Bb, ldB, n0 + 64, k0, N);
    }
    __syncthreads();

    f16x8 ah[MI];
    #pragma unroll
    for (int mi = 0; mi < MI; ++mi)
      ah[mi] = ldfrag(As, wr * (BM / 2) + mi * 16 + (lane & 15));
    #pragma unroll
    for (int ni = 0; ni < NI; ++ni) {
      f16x8 bh = ldfrag(Bs, wc * (BN / 2) + ni * 16 + (lane & 15));
      #pragma unroll
      for (int mi = 0; mi < MI; ++mi)
        acc[mi][ni] = __builtin_amdgcn_mfma_f32_16x16x32_f16(ah[mi], bh, acc[mi][ni], 0, 0, 0);
    }
    __syncthreads();
  }

  if (OUT == 4 || OUT == 5) {
    float* red = (float*)smem;  // safe: k-loop ended with __syncthreads
    #pragma unroll
    for (int ni = 0; ni < NI; ++ni) {
      float pm = 0.0f;  // relu floor
      #pragma unroll
      for (int mi = 0; mi < MI; ++mi)
        #pragma unroll
        for (int r = 0; r < 4; ++r)
          pm = fmaxf(pm, acc[mi][ni][r]);
      int g = wr * 4 + (lane >> 4);
      int col = wc * (BN / 2) + ni * 16 + (lane & 15);
      red[g * BN + col] = pm;
    }
    __syncthreads();
    if (OUT == 4) {
      if (t < BN) {
        float m = red[t];
        #pragma unroll
        for (int g = 1; g < 8; ++g) m = fmaxf(m, red[g * BN + t]);
        Cf[(long)(z * mtiles + by) * ldC + n0 + t] = m;
      }
    } else {
      constexpr int NGR = BM / 64, PG = 8 / NGR;
      if (t < NGR * BN) {
        int hh = t / BN, col = t - hh * BN;
        float m = red[(hh * PG) * BN + col];
        #pragma unroll
        for (int i = 1; i < PG; ++i) m = fmaxf(m, red[(hh * PG + i) * BN + col]);
        Cf[(long)((m0 >> 6) + hh) * ldC + n0 + col] = m;
      }
    }
    return;
  }

  #pragma unroll
  for (int mi = 0; mi < MI; ++mi) {
    #pragma unroll
    for (int r = 0; r < 4; ++r) {
      int grow = m0 + wr * (BM / 2) + mi * 16 + (lane >> 4) * 4 + r;
      #pragma unroll
      for (int ni = 0; ni < NI; ++ni) {
        int gcol = n0 + wc * (BN / 2) + ni * 16 + (lane & 15);
        float v = acc[mi][ni][r];
        if (OUT == 1) {
          int b = grow >> 6, q = grow & 63;
          long dst = (long)b * 131072 + (long)((gcol >> 10) * 64 + q) * 1024 + (gcol & 1023);
          Ch[dst] = f2h(v);
        } else if (OUT == 2) {
          if (grow < M) Ch[(long)z * sC + (long)grow * ldC + gcol] = f2h(v);
        } else if (OUT == 3) {
          long dst = (long)(grow >> 6) * 65536 + (long)gcol * 64 + (grow & 63);
          Ch[dst] = f2h(v);
        }
      }
    }
  }
}

// ---------------- g1: Pcat (128x64) || P3T (128x64), 768 homogeneous blocks ----------------

__global__ __launch_bounds__(256) void g1_kernel(
    const unsigned short* Q_hi, const unsigned short* Wcat, const unsigned short* W21T,
    unsigned short* Pcat, unsigned short* P3T)
{
  __shared__ char smem[12288];
  int bid = blockIdx.x;  // natural order: round-robin across XCDs
  if (bid < 512) {   // Pcat: M=2048,N=2048,K=1024, tile 128x64
    gemm_body<128, 64, 1, false>(smem, bid & 31, bid >> 5, 0,
        Q_hi, Wcat, nullptr, nullptr, Pcat,
        2048, 2048, 1024, 1024, 1024, 0, 0, 0, 0, 0);
  } else {           // P3T: M=2048,N=1024,K=1024, tile 128x64
    int b2 = bid - 512;
    gemm_body<128, 64, 3, false>(smem, b2 & 15, b2 >> 4, 0,
        Q_hi, W21T, nullptr, nullptr, P3T,
        2048, 1024, 1024, 1024, 1024, 0, 0, 0, 0, 0);
  }
}

// ---------------- g2: score partials = A@Pcat^T, tile 64x128, K-split x2 ----------------

__global__ __launch_bounds__(512) void g2_kernel(
    const float* __restrict__ Afeat, const unsigned short* __restrict__ Pcat,
    float* __restrict__ Spar)
{
  __shared__ char smem[12288];
  char* Ash = smem;           // 4KB
  char* Bs  = smem + 4096;    // 8KB

  int orig = blockIdx.x;            // 512 blocks; z-grouped for L2
  int xcd = orig & 7, idx = orig >> 3;
  int z   = xcd * 4 + (idx >> 4);   // 4 batches per XCD -> Pcat L2-resident
  int sub = idx & 15;
  int by  = sub >> 1, kh = sub & 1;
  const int m0 = by * 64, kb = kh * 512;
  const int t = threadIdx.x, lane = t & 63;
  const int wid = t >> 6, wr = wid >> 1, wc = wid & 1;

  const float* Ab = Afeat + (long)z * 524288;
  const unsigned short* Bbh = Pcat + (long)z * 131072;

  f32x4 acc[4];
  #pragma unroll
  for (int i = 0; i < 4; ++i) acc[i] = f32x4{0.f, 0.f, 0.f, 0.f};

  auto ldfrag = [&](const char* lbuf, int rr) -> f16x8 {
    int ob = rr * 64 + (lane >> 4) * 16;
    ob ^= ((ob >> 7) & 3) << 4;
    return *(const f16x8*)(lbuf + ob);
  };

  for (int k0 = kb; k0 < kb + 512; k0 += 32) {
    { // A: fp32 load + fp16 convert + 8B ds_write (512 thr cover 64 rows x 32 k)
      int ob = t * 8;
      int e  = ob ^ (((ob >> 7) & 3) << 4);
      int m  = e >> 6, ke = (e & 63) >> 1;
      float4 v = *(const float4*)(Ab + (long)(m0 + m) * 1024 + k0 + ke);
      ushort4 h;
      h.x = f2h(v.x); h.y = f2h(v.y); h.z = f2h(v.z); h.w = f2h(v.w);
      *(ushort4*)(Ash + ob) = h;
    }
    { // B: gload 8KB (512 threads x 16B)
      int ob = t * 16;
      int e  = ob ^ (((ob >> 7) & 3) << 4);
      int n  = e >> 6, kk = (e & 63) >> 1;
      const unsigned short* gp = Bbh + (long)n * 1024 + k0 + kk;
      char* lp = Bs + (t & ~63) * 16;
      __builtin_amdgcn_global_load_lds((gas_t)(const void*)gp, (las_t)(void*)lp, 16, 0, 0);
    }
    __syncthreads();

    f16x8 ah = ldfrag(Ash, wr * 16 + (lane & 15));
    #pragma unroll
    for (int ni = 0; ni < 4; ++ni) {
      f16x8 bh = ldfrag(Bs, wc * 64 + ni * 16 + (lane & 15));
      acc[ni] = __builtin_amdgcn_mfma_f32_16x16x32_f16(ah, bh, acc[ni], 0, 0, 0);
    }
    __syncthreads();
  }

  // write fp32 partial scores
  float* dst = Spar + (long)kh * 2097152 + (long)z * 65536;
  #pragma unroll
  for (int r = 0; r < 4; ++r) {
    int grow = m0 + wr * 16 + (lane >> 4) * 4 + r;
    long base = (long)grow * 128 + wc * 64 + (lane & 15);
    dst[base]      = acc[0][r];
    dst[base + 16] = acc[1][r];
    dst[base + 32] = acc[2][r];
    dst[base + 48] = acc[3][r];
  }
}

// ---------------- merged softmaxes over partial sums ----------------

__global__ __launch_bounds__(256) void softmax_both(const float* __restrict__ Sp,
    unsigned short* __restrict__ aq, unsigned short* __restrict__ qa)
{
  if (blockIdx.x < 4096) {
    int row  = blockIdx.x * 4 + (threadIdx.x >> 6);
    int lane = threadIdx.x & 63;
    long o = (long)row * 128 + lane;
    float v = Sp[o] + Sp[o + 2097152];
    float m = v;
    #pragma unroll
    for (int off = 32; off; off >>= 1) m = fmaxf(m, __shfl_xor(m, off));
    float e = __expf(v - m);
    float s = e;
    #pragma unroll
    for (int off = 32; off; off >>= 1) s += __shfl_xor(s, off);
    aq[(long)row * 64 + lane] = f2h(e / s);
  } else {
    int bq = blockIdx.x - 4096;
    int b = bq >> 6, q = bq & 63;
    int t = threadIdx.x;
    const float* base = Sp + (long)b * 65536 + 64 + q;
    float v0 = base[(long)t * 128]         + base[(long)t * 128 + 2097152];
    float v1 = base[(long)(t + 256) * 128] + base[(long)(t + 256) * 128 + 2097152];
    float m = fmaxf(v0, v1);
    #pragma unroll
    for (int off = 32; off; off >>= 1) m = fmaxf(m, __shfl_xor(m, off));
    __shared__ float sm[4], ss[4];
    int wid = t >> 6, lane = t & 63;
    if (lane == 0) sm[wid] = m;
    __syncthreads();
    float M = fmaxf(fmaxf(sm[0], sm[1]), fmaxf(sm[2], sm[3]));
    float e0 = __expf(v0 - M), e1 = __expf(v1 - M);
    float s = e0 + e1;
    #pragma unroll
    for (int off = 32; off; off >>= 1) s += __shfl_xor(s, off);
    if (lane == 0) ss[wid] = s;
    __syncthreads();
    float inv = 1.0f / ((ss[0] + ss[1]) + (ss[2] + ss[3]));
    qa[(long)bq * 512 + t]       = f2h(e0 * inv);
    qa[(long)bq * 512 + t + 256] = f2h(e1 * inv);
  }
}

// ---------------- g3: PmaxA || ctx, natural order ----------------

__global__ __launch_bounds__(256) void g3_kernel(
    const unsigned short* aq, const unsigned short* P3T, float* PmaxA,
    const unsigned short* qa, const float* Afeat, unsigned short* ctx)
{
  __shared__ char smem[16384];
  int bid = blockIdx.x;  // natural order (heterogeneous work types)
  if (bid < 1024) {  // PmaxA: per batch M=512,N=1024,K=64, tile 128x128
    gemm_body<128, 128, 4, false>(smem, bid & 7, (bid >> 3) & 3, bid >> 5,
        aq, P3T, nullptr, PmaxA, nullptr,
        512, 1024, 64, 64, 64, 1024, 32768L, 65536L, 0, 4);
  } else {           // ctx: per batch M=64,N=1024,K=512, tile 64x64, B = A fp32 (k-major)
    int b2 = bid - 1024;
    gemm_body<64, 64, 2, true>(smem, b2 & 15, 0, b2 >> 4,
        qa, nullptr, Afeat, nullptr, ctx,
        64, 1024, 512, 512, 1024, 1024, 32768L, 524288L, 65536L, 0);
  }
}

// ---------------- g4 + final ----------------

__global__ __launch_bounds__(256) void g4_kernel(
    const unsigned short* ctx, const unsigned short* W22T, float* PmaxQ)
{
  __shared__ char smem[8192];
  gemm_body<64, 64, 5, false>(smem, blockIdx.x, blockIdx.y, 0,
      ctx, W22T, nullptr, PmaxQ, nullptr,
      2048, 1024, 1024, 1024, 1024, 1024, 0, 0, 0, 0);
}

__global__ __launch_bounds__(256) void final_combine(
    const float* __restrict__ PmaxA, const float* __restrict__ PmaxQ, float* __restrict__ out)
{
  int idx = blockIdx.x * 256 + threadIdx.x;  // 32768
  int b = idx >> 10, h = idx & 1023;
  float m = PmaxA[(long)(b * 4) * 1024 + h];
  #pragma unroll
  for (int mt = 1; mt < 4; ++mt)
    m = fmaxf(m, PmaxA[(long)(b * 4 + mt) * 1024 + h]);
  out[idx] = 0.5f * m + 0.5f * PmaxQ[idx];
}

// ---------------- launch ----------------

extern "C" void kernel_launch(void* const* d_in, const int* in_sizes, int n_in,
                              void* d_out, int out_size, void* d_ws, size_t ws_size,
                              hipStream_t stream) {
  const float* Afeat = (const float*)d_in[0];
  const float* Qfeat = (const float*)d_in[1];
  const float* W11   = (const float*)d_in[2];
  const float* W12   = (const float*)d_in[3];
  const float* W21   = (const float*)d_in[4];
  const float* W22   = (const float*)d_in[5];
  float* out = (float*)d_out;

  char* w = (char*)d_ws;
  auto alloc = [&](long bytes) { char* p = w; w += bytes; return p; };
  unsigned short* Q_hi  = (unsigned short*)alloc(4194304);
  unsigned short* Wcat  = (unsigned short*)alloc(4194304);   // [2048][1024] fp16: W11 ; W12^T
  unsigned short* W21T  = (unsigned short*)alloc(2097152);
  unsigned short* W22T  = (unsigned short*)alloc(2097152);
  unsigned short* Pcat  = (unsigned short*)alloc(8388608);   // [32][128][1024]
  unsigned short* P3T   = (unsigned short*)alloc(4194304);   // [32][1024][64]
  float*          Spar  = (float*)alloc(16777216);           // [2][32][512][128]
  unsigned short* aq    = (unsigned short*)alloc(2097152);   // [32][512][64]
  unsigned short* qa    = (unsigned short*)alloc(2097152);   // [32][64][512]
  unsigned short* ctx   = (unsigned short*)alloc(4194304);   // [32][64][1024]
  float*          PmaxA = (float*)alloc(524288);             // [128][1024]
  float*          PmaxQ = (float*)alloc(131072);             // [32][1024]

  dim3 blk(256), tblk(32, 8);

  conv16<<<2048, blk, 0, stream>>>(Qfeat, Q_hi);
  prep_W<<<dim3(32, 32, 4), tblk, 0, stream>>>(W11, W12, W21, W22, Wcat, W21T, W22T);

  g1_kernel<<<768, blk, 0, stream>>>(Q_hi, Wcat, W21T, Pcat, P3T);
  g2_kernel<<<512, dim3(512), 0, stream>>>(Afeat, Pcat, Spar);
  softmax_both<<<6144, blk, 0, stream>>>(Spar, aq, qa);
  g3_kernel<<<1536, blk, 0, stream>>>(aq, P3T, PmaxA, qa, Afeat, ctx);
  g4_kernel<<<dim3(16, 32), blk, 0, stream>>>(ctx, W22T, PmaxQ);
  final_combine<<<128, blk, 0, stream>>>(PmaxA, PmaxQ, out);
}

// Round 10
// 102.032 us; speedup vs baseline: 1.9304x; 1.0817x over previous
//
#include <hip/hip_runtime.h>
#include <stdint.h>

// B=32, La=512, Lq=64, H=1024. Plain-fp16 pipeline (absmax 0.0078 vs thr 0.0456).
// BK=64: two 32-k chunks staged per barrier pair (half the vmcnt-drain events).
// prep_all: Wcat/W21T/W22T (z<4) + Q->fp16 (z>=4)                 [1 dispatch]
// g1: Pcat = Q@Wcat^T (128x64, remap) || P3T = (Q@W21)^T (128x64) [768 blocks]
// g2: score partials = A(fp32 reg-staged)@Pcat^T, K-split x2       [512 blocks]
// softmax_both: aq = rowsoftmax(Sp0+Sp1), qa = colsoftmax (fp16)
// g3: PmaxA = colmax(relu(aq@P3T^T)) || ctx = qa@A (A fp32 staged)
// g4: PmaxQ = colmax64(relu(ctx@W22T^T)) + fused final combine

using f16x8 = __attribute__((ext_vector_type(8))) _Float16;
using f32x4 = __attribute__((ext_vector_type(4))) float;
typedef const __attribute__((address_space(1))) void* gas_t;
typedef __attribute__((address_space(3))) void* las_t;

__device__ __forceinline__ unsigned short f2h(float x) {
  _Float16 h = (_Float16)x;
  return __builtin_bit_cast(unsigned short, h);
}

// ---------------- prep: z<4 -> W conversions; z>=4 -> Q fp32->fp16 ----------------

__global__ __launch_bounds__(256) void prep_all(
    const float* __restrict__ W11, const float* __restrict__ W12,
    const float* __restrict__ W21, const float* __restrict__ W22,
    const float* __restrict__ Qfeat,
    unsigned short* __restrict__ Wcat, unsigned short* __restrict__ W21T,
    unsigned short* __restrict__ W22T, unsigned short* __restrict__ Q_hi)
{
  int z = blockIdx.z;
  int tx = threadIdx.x, ty = threadIdx.y;
  if (z >= 4) {  // Q: 524288 float4 groups over 2048 virtual blocks
    int blk = (z - 4) * 1024 + blockIdx.y * 32 + blockIdx.x;
    int i = blk * 256 + ty * 32 + tx;
    float4 v = ((const float4*)Qfeat)[i];
    ushort4 h;
    h.x = f2h(v.x); h.y = f2h(v.y); h.z = f2h(v.z); h.w = f2h(v.w);
    ((ushort4*)Q_hi)[i] = h;
    return;
  }
  __shared__ float tile[32][33];
  const float* src = z == 0 ? W11 : z == 1 ? W12 : z == 2 ? W21 : W22;
  int r0 = blockIdx.y * 32, c0 = blockIdx.x * 32;
  #pragma unroll
  for (int i = 0; i < 4; ++i) {
    int r = r0 + ty + i * 8;
    float v = src[(long)r * 1024 + c0 + tx];
    tile[ty + i * 8][tx] = v;
    if (z == 0) Wcat[(long)r * 1024 + c0 + tx] = f2h(v);
  }
  __syncthreads();
  if (z > 0) {
    #pragma unroll
    for (int i = 0; i < 4; ++i) {
      float v = tile[tx][ty + i * 8];
      long o = (long)(c0 + ty + i * 8) * 1024 + r0 + tx;
      if (z == 1)      Wcat[1048576 + o] = f2h(v);
      else if (z == 2) W21T[o] = f2h(v);
      else             W22T[o] = f2h(v);
    }
  }
}

// ---------------- generic MFMA GEMM body (C = A @ B^T), BK=64, fp16 ----------------
// OUT: 1=Pcat remap, 2=fp16 (row<M), 3=transpose remap, 4=relu+colmax(BM),
// 6=relu+colmax64 + final combine (Bf reused as PmaxA input, Cf = out).
// BF32: B operand fp32 [K x ldB] k-major, staged->fp16.
template<int BM, int BN, int OUT, bool BF32>
__device__ __forceinline__ void gemm_body(
    char* smem, int bx, int by, int z,
    const unsigned short* __restrict__ Ah,
    const unsigned short* __restrict__ Bh, const float* __restrict__ Bf,
    float* __restrict__ Cf, unsigned short* __restrict__ Ch,
    int M, int N, int K, int ldA, int ldB, int ldC, long sA, long sB, long sC, int mtiles)
{
  constexpr int ACH = BM * 64, BCH = BN * 64;  // bytes per 32-k chunk
  constexpr int MI = BM / 32, NI = BN / 32;
  char* As0 = smem;
  char* As1 = smem + ACH;
  char* Bs0 = smem + 2 * ACH;
  char* Bs1 = Bs0 + BCH;

  const int m0 = by * BM, n0 = bx * BN;
  const int t = threadIdx.x, lane = t & 63;
  const int wid = t >> 6, wr = wid >> 1, wc = wid & 1;

  const unsigned short* Ab = Ah + (long)z * sA;
  const unsigned short* Bb = BF32 ? nullptr : Bh + (long)z * sB;
  const float* Bfb = BF32 ? Bf + (long)z * sB : nullptr;

  f32x4 acc[MI][NI];
  #pragma unroll
  for (int i = 0; i < MI; ++i)
    #pragma unroll
    for (int j = 0; j < NI; ++j)
      acc[i][j] = f32x4{0.f, 0.f, 0.f, 0.f};

  auto stage4k = [&](char* lbuf, const unsigned short* g, int ld, int row0, int k0, int rmax) {
    int ob = t * 16;
    int e  = ob ^ (((ob >> 7) & 3) << 4);
    int m  = e >> 6, k = (e & 63) >> 1;
    int row = row0 + m; row = row < rmax ? row : rmax - 1;
    const unsigned short* gp = g + (long)row * ld + k0 + k;
    char* lp = lbuf + (t & ~63) * 16;  // wave-uniform; HW adds lane*16
    __builtin_amdgcn_global_load_lds((gas_t)(const void*)gp, (las_t)(void*)lp, 16, 0, 0);
  };
  auto stageB_f32 = [&](char* lbuf, const float* g, int ld, int nb, int k0) {
    int ob = t * 16;
    int e  = ob ^ (((ob >> 7) & 3) << 4);
    int n  = e >> 6, kb = (e & 63) >> 1;
    f16x8 pk;
    #pragma unroll
    for (int j = 0; j < 8; ++j) {
      float v = g[(long)(k0 + kb + j) * ld + nb + n];
      pk[j] = (_Float16)v;
    }
    *(f16x8*)(lbuf + ob) = pk;
  };
  auto ldfrag = [&](const char* lbuf, int rr) -> f16x8 {
    int ob = rr * 64 + (lane >> 4) * 16;
    ob ^= ((ob >> 7) & 3) << 4;
    return *(const f16x8*)(lbuf + ob);
  };
  auto compute32 = [&](const char* Ac, const char* Bc) {
    f16x8 ah[MI];
    #pragma unroll
    for (int mi = 0; mi < MI; ++mi)
      ah[mi] = ldfrag(Ac, wr * (BM / 2) + mi * 16 + (lane & 15));
    #pragma unroll
    for (int ni = 0; ni < NI; ++ni) {
      f16x8 bh = ldfrag(Bc, wc * (BN / 2) + ni * 16 + (lane & 15));
      #pragma unroll
      for (int mi = 0; mi < MI; ++mi)
        acc[mi][ni] = __builtin_amdgcn_mfma_f32_16x16x32_f16(ah[mi], bh, acc[mi][ni], 0, 0, 0);
    }
  };

  for (int k0 = 0; k0 < K; k0 += 64) {
    stage4k(As0, Ab, ldA, m0, k0, M);
    if (BM == 128) stage4k(As0 + 4096, Ab, ldA, m0 + 64, k0, M);
    stage4k(As1, Ab, ldA, m0, k0 + 32, M);
    if (BM == 128) stage4k(As1 + 4096, Ab, ldA, m0 + 64, k0 + 32, M);
    if (BF32) {
      stageB_f32(Bs0, Bfb, ldB, n0, k0);
      stageB_f32(Bs1, Bfb, ldB, n0, k0 + 32);
    } else {
      stage4k(Bs0, Bb, ldB, n0, k0, N);
      if (BN == 128) stage4k(Bs0 + 4096, Bb, ldB, n0 + 64, k0, N);
      stage4k(Bs1, Bb, ldB, n0, k0 + 32, N);
      if (BN == 128) stage4k(Bs1 + 4096, Bb, ldB, n0 + 64, k0 + 32, N);
    }
    __syncthreads();
    compute32(As0, Bs0);
    compute32(As1, Bs1);
    __syncthreads();
  }

  if (OUT == 4 || OUT == 6) {
    float* red = (float*)smem;  // safe: k-loop ended with __syncthreads
    #pragma unroll
    for (int ni = 0; ni < NI; ++ni) {
      float pm = 0.0f;  // relu floor
      #pragma unroll
      for (int mi = 0; mi < MI; ++mi)
        #pragma unroll
        for (int r = 0; r < 4; ++r)
          pm = fmaxf(pm, acc[mi][ni][r]);
      int g = wr * 4 + (lane >> 4);
      int col = wc * (BN / 2) + ni * 16 + (lane & 15);
      red[g * BN + col] = pm;
    }
    __syncthreads();
    if (OUT == 4) {
      if (t < BN) {
        float m = red[t];
        #pragma unroll
        for (int g = 1; g < 8; ++g) m = fmaxf(m, red[g * BN + t]);
        Cf[(long)(z * mtiles + by) * ldC + n0 + t] = m;
      }
    } else {  // OUT == 6: BM=BN=64, by = batch; Bf = PmaxA [128][1024]; Cf = out
      if (t < BN) {
        float pq = red[t];
        #pragma unroll
        for (int g = 1; g < 8; ++g) pq = fmaxf(pq, red[g * BN + t]);
        float pa = Bf[(long)(by * 4) * 1024 + n0 + t];
        #pragma unroll
        for (int mt = 1; mt < 4; ++mt)
          pa = fmaxf(pa, Bf[(long)(by * 4 + mt) * 1024 + n0 + t]);
        Cf[(long)by * 1024 + n0 + t] = 0.5f * pa + 0.5f * pq;
      }
    }
    return;
  }

  #pragma unroll
  for (int mi = 0; mi < MI; ++mi) {
    #pragma unroll
    for (int r = 0; r < 4; ++r) {
      int grow = m0 + wr * (BM / 2) + mi * 16 + (lane >> 4) * 4 + r;
      #pragma unroll
      for (int ni = 0; ni < NI; ++ni) {
        int gcol = n0 + wc * (BN / 2) + ni * 16 + (lane & 15);
        float v = acc[mi][ni][r];
        if (OUT == 1) {
          int b = grow >> 6, q = grow & 63;
          long dst = (long)b * 131072 + (long)((gcol >> 10) * 64 + q) * 1024 + (gcol & 1023);
          Ch[dst] = f2h(v);
        } else if (OUT == 2) {
          if (grow < M) Ch[(long)z * sC + (long)grow * ldC + gcol] = f2h(v);
        } else if (OUT == 3) {
          long dst = (long)(grow >> 6) * 65536 + (long)gcol * 64 + (grow & 63);
          Ch[dst] = f2h(v);
        }
      }
    }
  }
}

// ---------------- g1: Pcat (128x64) || P3T (128x64), 768 blocks, natural ----------------

__global__ __launch_bounds__(256) void g1_kernel(
    const unsigned short* Q_hi, const unsigned short* Wcat, const unsigned short* W21T,
    unsigned short* Pcat, unsigned short* P3T)
{
  __shared__ char smem[24576];
  int bid = blockIdx.x;  // natural order: round-robin across XCDs
  if (bid < 512) {   // Pcat: M=2048,N=2048,K=1024, tile 128x64
    gemm_body<128, 64, 1, false>(smem, bid & 31, bid >> 5, 0,
        Q_hi, Wcat, nullptr, nullptr, Pcat,
        2048, 2048, 1024, 1024, 1024, 0, 0, 0, 0, 0);
  } else {           // P3T: M=2048,N=1024,K=1024, tile 128x64
    int b2 = bid - 512;
    gemm_body<128, 64, 3, false>(smem, b2 & 15, b2 >> 4, 0,
        Q_hi, W21T, nullptr, nullptr, P3T,
        2048, 1024, 1024, 1024, 1024, 0, 0, 0, 0, 0);
  }
}

// ---------------- g2: score partials = A@Pcat^T, tile 64x128, K-split x2, BK=64 ----------------

__global__ __launch_bounds__(512) void g2_kernel(
    const float* __restrict__ Afeat, const unsigned short* __restrict__ Pcat,
    float* __restrict__ Spar)
{
  __shared__ char smem[24576];
  char* Ash0 = smem;            // 4KB
  char* Ash1 = smem + 4096;     // 4KB
  char* Bs0  = smem + 8192;     // 8KB
  char* Bs1  = smem + 16384;    // 8KB

  int orig = blockIdx.x;            // 512 blocks; z-grouped for L2
  int xcd = orig & 7, idx = orig >> 3;
  int z   = xcd * 4 + (idx >> 4);   // 4 batches per XCD -> Pcat L2-resident
  int sub = idx & 15;
  int by  = sub >> 1, kh = sub & 1;
  const int m0 = by * 64, kb = kh * 512;
  const int t = threadIdx.x, lane = t & 63;
  const int wid = t >> 6, wr = wid >> 1, wc = wid & 1;

  const float* Ab = Afeat + (long)z * 524288;
  const unsigned short* Bbh = Pcat + (long)z * 131072;

  f32x4 acc[4];
  #pragma unroll
  for (int i = 0; i < 4; ++i) acc[i] = f32x4{0.f, 0.f, 0.f, 0.f};

  auto ldfrag = [&](const char* lbuf, int rr) -> f16x8 {
    int ob = rr * 64 + (lane >> 4) * 16;
    ob ^= ((ob >> 7) & 3) << 4;
    return *(const f16x8*)(lbuf + ob);
  };
  auto stageA = [&](char* lbuf, int k0) {
    int ob = t * 8;
    int e  = ob ^ (((ob >> 7) & 3) << 4);
    int m  = e >> 6, ke = (e & 63) >> 1;
    float4 v = *(const float4*)(Ab + (long)(m0 + m) * 1024 + k0 + ke);
    ushort4 h;
    h.x = f2h(v.x); h.y = f2h(v.y); h.z = f2h(v.z); h.w = f2h(v.w);
    *(ushort4*)(lbuf + ob) = h;
  };
  auto stageB = [&](char* lbuf, int k0) {
    int ob = t * 16;
    int e  = ob ^ (((ob >> 7) & 3) << 4);
    int n  = e >> 6, kk = (e & 63) >> 1;
    const unsigned short* gp = Bbh + (long)n * 1024 + k0 + kk;
    char* lp = lbuf + (t & ~63) * 16;
    __builtin_amdgcn_global_load_lds((gas_t)(const void*)gp, (las_t)(void*)lp, 16, 0, 0);
  };
  auto compute32 = [&](const char* Ac, const char* Bc) {
    f16x8 ah = ldfrag(Ac, wr * 16 + (lane & 15));
    #pragma unroll
    for (int ni = 0; ni < 4; ++ni) {
      f16x8 bh = ldfrag(Bc, wc * 64 + ni * 16 + (lane & 15));
      acc[ni] = __builtin_amdgcn_mfma_f32_16x16x32_f16(ah, bh, acc[ni], 0, 0, 0);
    }
  };

  for (int k0 = kb; k0 < kb + 512; k0 += 64) {
    stageA(Ash0, k0);
    stageA(Ash1, k0 + 32);
    stageB(Bs0, k0);
    stageB(Bs1, k0 + 32);
    __syncthreads();
    compute32(Ash0, Bs0);
    compute32(Ash1, Bs1);
    __syncthreads();
  }

  float* dst = Spar + (long)kh * 2097152 + (long)z * 65536;
  #pragma unroll
  for (int r = 0; r < 4; ++r) {
    int grow = m0 + wr * 16 + (lane >> 4) * 4 + r;
    long base = (long)grow * 128 + wc * 64 + (lane & 15);
    dst[base]      = acc[0][r];
    dst[base + 16] = acc[1][r];
    dst[base + 32] = acc[2][r];
    dst[base + 48] = acc[3][r];
  }
}

// ---------------- merged softmaxes over partial sums ----------------

__global__ __launch_bounds__(256) void softmax_both(const float* __restrict__ Sp,
    unsigned short* __restrict__ aq, unsigned short* __restrict__ qa)
{
  if (blockIdx.x < 4096) {
    int row  = blockIdx.x * 4 + (threadIdx.x >> 6);
    int lane = threadIdx.x & 63;
    long o = (long)row * 128 + lane;
    float v = Sp[o] + Sp[o + 2097152];
    float m = v;
    #pragma unroll
    for (int off = 32; off; off >>= 1) m = fmaxf(m, __shfl_xor(m, off));
    float e = __expf(v - m);
    float s = e;
    #pragma unroll
    for (int off = 32; off; off >>= 1) s += __shfl_xor(s, off);
    aq[(long)row * 64 + lane] = f2h(e / s);
  } else {
    int bq = blockIdx.x - 4096;
    int b = bq >> 6, q = bq & 63;
    int t = threadIdx.x;
    const float* base = Sp + (long)b * 65536 + 64 + q;
    float v0 = base[(long)t * 128]         + base[(long)t * 128 + 2097152];
    float v1 = base[(long)(t + 256) * 128] + base[(long)(t + 256) * 128 + 2097152];
    float m = fmaxf(v0, v1);
    #pragma unroll
    for (int off = 32; off; off >>= 1) m = fmaxf(m, __shfl_xor(m, off));
    __shared__ float sm[4], ss[4];
    int wid = t >> 6, lane = t & 63;
    if (lane == 0) sm[wid] = m;
    __syncthreads();
    float M = fmaxf(fmaxf(sm[0], sm[1]), fmaxf(sm[2], sm[3]));
    float e0 = __expf(v0 - M), e1 = __expf(v1 - M);
    float s = e0 + e1;
    #pragma unroll
    for (int off = 32; off; off >>= 1) s += __shfl_xor(s, off);
    if (lane == 0) ss[wid] = s;
    __syncthreads();
    float inv = 1.0f / ((ss[0] + ss[1]) + (ss[2] + ss[3]));
    qa[(long)bq * 512 + t]       = f2h(e0 * inv);
    qa[(long)bq * 512 + t + 256] = f2h(e1 * inv);
  }
}

// ---------------- g3: PmaxA || ctx, natural order ----------------

__global__ __launch_bounds__(256) void g3_kernel(
    const unsigned short* aq, const unsigned short* P3T, float* PmaxA,
    const unsigned short* qa, const float* Afeat, unsigned short* ctx)
{
  __shared__ char smem[32768];
  int bid = blockIdx.x;  // natural order (heterogeneous work types)
  if (bid < 1024) {  // PmaxA: per batch M=512,N=1024,K=64, tile 128x128
    gemm_body<128, 128, 4, false>(smem, bid & 7, (bid >> 3) & 3, bid >> 5,
        aq, P3T, nullptr, PmaxA, nullptr,
        512, 1024, 64, 64, 64, 1024, 32768L, 65536L, 0, 4);
  } else {           // ctx: per batch M=64,N=1024,K=512, tile 64x64, B = A fp32 (k-major)
    int b2 = bid - 1024;
    gemm_body<64, 64, 2, true>(smem, b2 & 15, 0, b2 >> 4,
        qa, nullptr, Afeat, nullptr, ctx,
        64, 1024, 512, 512, 1024, 1024, 32768L, 524288L, 65536L, 0);
  }
}

// ---------------- g4: PmaxQ colmax + fused final combine ----------------

__global__ __launch_bounds__(256) void g4_kernel(
    const unsigned short* ctx, const unsigned short* W22T,
    const float* PmaxA, float* out)
{
  __shared__ char smem[16384];
  // OUT==6: Bf carries PmaxA, Cf carries out
  gemm_body<64, 64, 6, false>(smem, blockIdx.x, blockIdx.y, 0,
      ctx, W22T, PmaxA, out, nullptr,
      2048, 1024, 1024, 1024, 1024, 1024, 0, 0, 0, 0);
}

// ---------------- launch ----------------

extern "C" void kernel_launch(void* const* d_in, const int* in_sizes, int n_in,
                              void* d_out, int out_size, void* d_ws, size_t ws_size,
                              hipStream_t stream) {
  const float* Afeat = (const float*)d_in[0];
  const float* Qfeat = (const float*)d_in[1];
  const float* W11   = (const float*)d_in[2];
  const float* W12   = (const float*)d_in[3];
  const float* W21   = (const float*)d_in[4];
  const float* W22   = (const float*)d_in[5];
  float* out = (float*)d_out;

  char* w = (char*)d_ws;
  auto alloc = [&](long bytes) { char* p = w; w += bytes; return p; };
  unsigned short* Q_hi  = (unsigned short*)alloc(4194304);
  unsigned short* Wcat  = (unsigned short*)alloc(4194304);   // [2048][1024] fp16: W11 ; W12^T
  unsigned short* W21T  = (unsigned short*)alloc(2097152);
  unsigned short* W22T  = (unsigned short*)alloc(2097152);
  unsigned short* Pcat  = (unsigned short*)alloc(8388608);   // [32][128][1024]
  unsigned short* P3T   = (unsigned short*)alloc(4194304);   // [32][1024][64]
  float*          Spar  = (float*)alloc(16777216);           // [2][32][512][128]
  unsigned short* aq    = (unsigned short*)alloc(2097152);   // [32][512][64]
  unsigned short* qa    = (unsigned short*)alloc(2097152);   // [32][64][512]
  unsigned short* ctx   = (unsigned short*)alloc(4194304);   // [32][64][1024]
  float*          PmaxA = (float*)alloc(524288);             // [128][1024]

  dim3 blk(256), tblk(32, 8);

  prep_all<<<dim3(32, 32, 6), tblk, 0, stream>>>(W11, W12, W21, W22, Qfeat,
                                                 Wcat, W21T, W22T, Q_hi);
  g1_kernel<<<768, blk, 0, stream>>>(Q_hi, Wcat, W21T, Pcat, P3T);
  g2_kernel<<<512, dim3(512), 0, stream>>>(Afeat, Pcat, Spar);
  softmax_both<<<6144, blk, 0, stream>>>(Spar, aq, qa);
  g3_kernel<<<1536, blk, 0, stream>>>(aq, P3T, PmaxA, qa, Afeat, ctx);
  g4_kernel<<<dim3(16, 32), blk, 0, stream>>>(ctx, W22T, PmaxA, out);
}

// Round 11
// 95.854 us; speedup vs baseline: 2.0548x; 1.0645x over previous
//
#include <hip/hip_runtime.h>
#include <stdint.h>

// B=32, La=512, Lq=64, H=1024. Plain-fp16 pipeline (absmax 0.0078 vs thr 0.0456).
// prep_all: Wcat/W21T/W22T (z<4) + Q->fp16 (z>=4)
// g1: Pcat = Q@Wcat^T (128x64, remap) || P3T = (Q@W21)^T (128x64) [768 blocks]
// g2: scores = A@Pcat^T, tile 32x128 full-K; FUSED aq row-softmax; qa half -> Spar fp32
// softmax_cols: qa = colsoftmax(Spar) fp16
// g3: PmaxA = colmax(relu(aq@P3T^T)) LDS-FREE direct-fragment (K=64) || ctx = qa@A
// g4: PmaxQ = colmax64(relu(ctx@W22T^T)) + fused final combine

using f16x8 = __attribute__((ext_vector_type(8))) _Float16;
using f32x4 = __attribute__((ext_vector_type(4))) float;
typedef const __attribute__((address_space(1))) void* gas_t;
typedef __attribute__((address_space(3))) void* las_t;

__device__ __forceinline__ unsigned short f2h(float x) {
  _Float16 h = (_Float16)x;
  return __builtin_bit_cast(unsigned short, h);
}

// ---------------- prep: z<4 -> W conversions; z>=4 -> Q fp32->fp16 ----------------

__global__ __launch_bounds__(256) void prep_all(
    const float* __restrict__ W11, const float* __restrict__ W12,
    const float* __restrict__ W21, const float* __restrict__ W22,
    const float* __restrict__ Qfeat,
    unsigned short* __restrict__ Wcat, unsigned short* __restrict__ W21T,
    unsigned short* __restrict__ W22T, unsigned short* __restrict__ Q_hi)
{
  int z = blockIdx.z;
  int tx = threadIdx.x, ty = threadIdx.y;
  if (z >= 4) {  // Q: 524288 float4 groups over 2048 virtual blocks
    int blk = (z - 4) * 1024 + blockIdx.y * 32 + blockIdx.x;
    int i = blk * 256 + ty * 32 + tx;
    float4 v = ((const float4*)Qfeat)[i];
    ushort4 h;
    h.x = f2h(v.x); h.y = f2h(v.y); h.z = f2h(v.z); h.w = f2h(v.w);
    ((ushort4*)Q_hi)[i] = h;
    return;
  }
  __shared__ float tile[32][33];
  const float* src = z == 0 ? W11 : z == 1 ? W12 : z == 2 ? W21 : W22;
  int r0 = blockIdx.y * 32, c0 = blockIdx.x * 32;
  #pragma unroll
  for (int i = 0; i < 4; ++i) {
    int r = r0 + ty + i * 8;
    float v = src[(long)r * 1024 + c0 + tx];
    tile[ty + i * 8][tx] = v;
    if (z == 0) Wcat[(long)r * 1024 + c0 + tx] = f2h(v);
  }
  __syncthreads();
  if (z > 0) {
    #pragma unroll
    for (int i = 0; i < 4; ++i) {
      float v = tile[tx][ty + i * 8];
      long o = (long)(c0 + ty + i * 8) * 1024 + r0 + tx;
      if (z == 1)      Wcat[1048576 + o] = f2h(v);
      else if (z == 2) W21T[o] = f2h(v);
      else             W22T[o] = f2h(v);
    }
  }
}

// ---------------- generic MFMA GEMM body (C = A @ B^T), BK=64, fp16 ----------------
// OUT: 1=Pcat remap, 2=fp16 (row<M), 3=transpose remap,
// 6=relu+colmax64 + final combine (Bf = PmaxA input, Cf = out).
// BF32: B operand fp32 [K x ldB] k-major, staged->fp16.
template<int BM, int BN, int OUT, bool BF32>
__device__ __forceinline__ void gemm_body(
    char* smem, int bx, int by, int z,
    const unsigned short* __restrict__ Ah,
    const unsigned short* __restrict__ Bh, const float* __restrict__ Bf,
    float* __restrict__ Cf, unsigned short* __restrict__ Ch,
    int M, int N, int K, int ldA, int ldB, int ldC, long sA, long sB, long sC)
{
  constexpr int ACH = BM * 64, BCH = BN * 64;  // bytes per 32-k chunk
  constexpr int MI = BM / 32, NI = BN / 32;
  char* As0 = smem;
  char* As1 = smem + ACH;
  char* Bs0 = smem + 2 * ACH;
  char* Bs1 = Bs0 + BCH;

  const int m0 = by * BM, n0 = bx * BN;
  const int t = threadIdx.x, lane = t & 63;
  const int wid = t >> 6, wr = wid >> 1, wc = wid & 1;

  const unsigned short* Ab = Ah + (long)z * sA;
  const unsigned short* Bb = BF32 ? nullptr : Bh + (long)z * sB;
  const float* Bfb = BF32 ? Bf + (long)z * sB : nullptr;

  f32x4 acc[MI][NI];
  #pragma unroll
  for (int i = 0; i < MI; ++i)
    #pragma unroll
    for (int j = 0; j < NI; ++j)
      acc[i][j] = f32x4{0.f, 0.f, 0.f, 0.f};

  auto stage4k = [&](char* lbuf, const unsigned short* g, int ld, int row0, int k0, int rmax) {
    int ob = t * 16;
    int e  = ob ^ (((ob >> 7) & 3) << 4);
    int m  = e >> 6, k = (e & 63) >> 1;
    int row = row0 + m; row = row < rmax ? row : rmax - 1;
    const unsigned short* gp = g + (long)row * ld + k0 + k;
    char* lp = lbuf + (t & ~63) * 16;  // wave-uniform; HW adds lane*16
    __builtin_amdgcn_global_load_lds((gas_t)(const void*)gp, (las_t)(void*)lp, 16, 0, 0);
  };
  auto stageB_f32 = [&](char* lbuf, const float* g, int ld, int nb, int k0) {
    int ob = t * 16;
    int e  = ob ^ (((ob >> 7) & 3) << 4);
    int n  = e >> 6, kb = (e & 63) >> 1;
    f16x8 pk;
    #pragma unroll
    for (int j = 0; j < 8; ++j) {
      float v = g[(long)(k0 + kb + j) * ld + nb + n];
      pk[j] = (_Float16)v;
    }
    *(f16x8*)(lbuf + ob) = pk;
  };
  auto ldfrag = [&](const char* lbuf, int rr) -> f16x8 {
    int ob = rr * 64 + (lane >> 4) * 16;
    ob ^= ((ob >> 7) & 3) << 4;
    return *(const f16x8*)(lbuf + ob);
  };
  auto compute32 = [&](const char* Ac, const char* Bc) {
    f16x8 ah[MI];
    #pragma unroll
    for (int mi = 0; mi < MI; ++mi)
      ah[mi] = ldfrag(Ac, wr * (BM / 2) + mi * 16 + (lane & 15));
    #pragma unroll
    for (int ni = 0; ni < NI; ++ni) {
      f16x8 bh = ldfrag(Bc, wc * (BN / 2) + ni * 16 + (lane & 15));
      #pragma unroll
      for (int mi = 0; mi < MI; ++mi)
        acc[mi][ni] = __builtin_amdgcn_mfma_f32_16x16x32_f16(ah[mi], bh, acc[mi][ni], 0, 0, 0);
    }
  };

  for (int k0 = 0; k0 < K; k0 += 64) {
    stage4k(As0, Ab, ldA, m0, k0, M);
    if (BM == 128) stage4k(As0 + 4096, Ab, ldA, m0 + 64, k0, M);
    stage4k(As1, Ab, ldA, m0, k0 + 32, M);
    if (BM == 128) stage4k(As1 + 4096, Ab, ldA, m0 + 64, k0 + 32, M);
    if (BF32) {
      stageB_f32(Bs0, Bfb, ldB, n0, k0);
      stageB_f32(Bs1, Bfb, ldB, n0, k0 + 32);
    } else {
      stage4k(Bs0, Bb, ldB, n0, k0, N);
      stage4k(Bs1, Bb, ldB, n0, k0 + 32, N);
    }
    __syncthreads();
    compute32(As0, Bs0);
    compute32(As1, Bs1);
    __syncthreads();
  }

  if (OUT == 6) {
    float* red = (float*)smem;  // safe: k-loop ended with __syncthreads
    #pragma unroll
    for (int ni = 0; ni < NI; ++ni) {
      float pm = 0.0f;  // relu floor
      #pragma unroll
      for (int mi = 0; mi < MI; ++mi)
        #pragma unroll
        for (int r = 0; r < 4; ++r)
          pm = fmaxf(pm, acc[mi][ni][r]);
      int g = wr * 4 + (lane >> 4);
      int col = wc * (BN / 2) + ni * 16 + (lane & 15);
      red[g * BN + col] = pm;
    }
    __syncthreads();
    if (t < BN) {  // BM=BN=64, by = batch; Bf = PmaxA [128][1024]; Cf = out
      float pq = red[t];
      #pragma unroll
      for (int g = 1; g < 8; ++g) pq = fmaxf(pq, red[g * BN + t]);
      float pa = Bf[(long)(by * 4) * 1024 + n0 + t];
      #pragma unroll
      for (int mt = 1; mt < 4; ++mt)
        pa = fmaxf(pa, Bf[(long)(by * 4 + mt) * 1024 + n0 + t]);
      Cf[(long)by * 1024 + n0 + t] = 0.5f * pa + 0.5f * pq;
    }
    return;
  }

  #pragma unroll
  for (int mi = 0; mi < MI; ++mi) {
    #pragma unroll
    for (int r = 0; r < 4; ++r) {
      int grow = m0 + wr * (BM / 2) + mi * 16 + (lane >> 4) * 4 + r;
      #pragma unroll
      for (int ni = 0; ni < NI; ++ni) {
        int gcol = n0 + wc * (BN / 2) + ni * 16 + (lane & 15);
        float v = acc[mi][ni][r];
        if (OUT == 1) {
          int b = grow >> 6, q = grow & 63;
          long dst = (long)b * 131072 + (long)((gcol >> 10) * 64 + q) * 1024 + (gcol & 1023);
          Ch[dst] = f2h(v);
        } else if (OUT == 2) {
          if (grow < M) Ch[(long)z * sC + (long)grow * ldC + gcol] = f2h(v);
        } else if (OUT == 3) {
          long dst = (long)(grow >> 6) * 65536 + (long)gcol * 64 + (grow & 63);
          Ch[dst] = f2h(v);
        }
      }
    }
  }
}

// ---------------- g1: Pcat (128x64) || P3T (128x64), 768 blocks, natural ----------------

__global__ __launch_bounds__(256) void g1_kernel(
    const unsigned short* Q_hi, const unsigned short* Wcat, const unsigned short* W21T,
    unsigned short* Pcat, unsigned short* P3T)
{
  __shared__ char smem[24576];
  int bid = blockIdx.x;  // natural order: round-robin across XCDs
  if (bid < 512) {   // Pcat: M=2048,N=2048,K=1024, tile 128x64
    gemm_body<128, 64, 1, false>(smem, bid & 31, bid >> 5, 0,
        Q_hi, Wcat, nullptr, nullptr, Pcat,
        2048, 2048, 1024, 1024, 1024, 0, 0, 0, 0);
  } else {           // P3T: M=2048,N=1024,K=1024, tile 128x64
    int b2 = bid - 512;
    gemm_body<128, 64, 3, false>(smem, b2 & 15, b2 >> 4, 0,
        Q_hi, W21T, nullptr, nullptr, P3T,
        2048, 1024, 1024, 1024, 1024, 0, 0, 0, 0);
  }
}

// ---------------- g2: scores, tile 32x128 full-K, fused aq softmax ----------------

__global__ __launch_bounds__(512) void g2_kernel(
    const float* __restrict__ Afeat, const unsigned short* __restrict__ Pcat,
    unsigned short* __restrict__ aq, float* __restrict__ Spar)
{
  __shared__ char smem[20480];
  char* A0 = smem;            // 2KB (32 rows x 32 k fp16)
  char* A1 = smem + 2048;     // 2KB
  char* B0 = smem + 4096;     // 8KB (128 rows x 32 k)
  char* B1 = smem + 12288;    // 8KB

  int orig = blockIdx.x;            // 512 blocks; z-grouped for Pcat L2 residence
  int xcd = orig & 7, idx = orig >> 3;
  int z   = xcd * 4 + (idx >> 4);
  int mt  = idx & 15;
  const int m0 = mt * 32;
  const int t = threadIdx.x, lane = t & 63;
  const int wid = t >> 6, wr = wid >> 2, wc = wid & 3;  // 2 x 4 waves

  const float* Ab = Afeat + (long)z * 524288;
  const unsigned short* Bb = Pcat + (long)z * 131072;

  f32x4 acc[2];
  acc[0] = f32x4{0.f, 0.f, 0.f, 0.f};
  acc[1] = f32x4{0.f, 0.f, 0.f, 0.f};

  auto ldfrag = [&](const char* lbuf, int rr) -> f16x8 {
    int ob = rr * 64 + (lane >> 4) * 16;
    ob ^= ((ob >> 7) & 3) << 4;
    return *(const f16x8*)(lbuf + ob);
  };
  auto stageA = [&](int k0) {  // both 32-k chunks: t<256 -> A0, t>=256 -> A1
    int half = t >> 8, tt = t & 255;
    int ob = tt * 8;
    int e  = ob ^ (((ob >> 7) & 3) << 4);
    int m  = e >> 6, ke = (e & 63) >> 1;
    float4 v = *(const float4*)(Ab + (long)(m0 + m) * 1024 + k0 + half * 32 + ke);
    ushort4 h;
    h.x = f2h(v.x); h.y = f2h(v.y); h.z = f2h(v.z); h.w = f2h(v.w);
    *(ushort4*)((half ? A1 : A0) + ob) = h;
  };
  auto stageB = [&](char* lbuf, int k0) {
    int ob = t * 16;
    int e  = ob ^ (((ob >> 7) & 3) << 4);
    int n  = e >> 6, kk = (e & 63) >> 1;
    const unsigned short* gp = Bb + (long)n * 1024 + k0 + kk;
    char* lp = lbuf + (t & ~63) * 16;
    __builtin_amdgcn_global_load_lds((gas_t)(const void*)gp, (las_t)(void*)lp, 16, 0, 0);
  };
  auto compute32 = [&](const char* Ac, const char* Bc) {
    f16x8 ah = ldfrag(Ac, wr * 16 + (lane & 15));
    #pragma unroll
    for (int ni = 0; ni < 2; ++ni) {
      f16x8 bh = ldfrag(Bc, wc * 32 + ni * 16 + (lane & 15));
      acc[ni] = __builtin_amdgcn_mfma_f32_16x16x32_f16(ah, bh, acc[ni], 0, 0, 0);
    }
  };

  for (int k0 = 0; k0 < 1024; k0 += 64) {
    stageA(k0);
    stageB(B0, k0);
    stageB(B1, k0 + 32);
    __syncthreads();
    compute32(A0, B0);
    compute32(A1, B1);
    __syncthreads();
  }

  // epilogue: gather full rows in LDS, fused aq row-softmax, qa half -> Spar fp32
  float* red = (float*)smem;  // [32][128] = 16KB; safe (loop ended with barrier)
  #pragma unroll
  for (int ni = 0; ni < 2; ++ni)
    #pragma unroll
    for (int r = 0; r < 4; ++r) {
      int lrow = wr * 16 + (lane >> 4) * 4 + r;
      int col  = wc * 32 + ni * 16 + (lane & 15);
      red[lrow * 128 + col] = acc[ni][r];
    }
  __syncthreads();

  int row = t >> 4, cg = (t & 15) * 4;   // 16 threads per row, 4 cols each
  float a0 = red[row * 128 + cg],     a1 = red[row * 128 + cg + 1];
  float a2 = red[row * 128 + cg + 2], a3 = red[row * 128 + cg + 3];
  float4 vq = *(float4*)&red[row * 128 + 64 + cg];
  float mx = fmaxf(fmaxf(a0, a1), fmaxf(a2, a3));
  #pragma unroll
  for (int off = 8; off; off >>= 1) mx = fmaxf(mx, __shfl_xor(mx, off));
  float e0 = __expf(a0 - mx), e1 = __expf(a1 - mx);
  float e2 = __expf(a2 - mx), e3 = __expf(a3 - mx);
  float s = (e0 + e1) + (e2 + e3);
  #pragma unroll
  for (int off = 8; off; off >>= 1) s += __shfl_xor(s, off);
  float inv = 1.0f / s;
  ushort4 h;
  h.x = f2h(e0 * inv); h.y = f2h(e1 * inv); h.z = f2h(e2 * inv); h.w = f2h(e3 * inv);
  long base = (long)z * 32768 + (long)(m0 + row) * 64 + cg;
  *(ushort4*)(aq + base) = h;
  *(float4*)(Spar + base) = vq;
}

// ---------------- qa col-softmax (single buffer) ----------------

__global__ __launch_bounds__(256) void softmax_cols(const float* __restrict__ Sp,
                                                    unsigned short* __restrict__ qa)
{
  int bq = blockIdx.x;
  int b = bq >> 6, q = bq & 63;
  int t = threadIdx.x;
  const float* base = Sp + (long)b * 32768 + q;
  float v0 = base[(long)t * 64];
  float v1 = base[(long)(t + 256) * 64];
  float m = fmaxf(v0, v1);
  #pragma unroll
  for (int off = 32; off; off >>= 1) m = fmaxf(m, __shfl_xor(m, off));
  __shared__ float sm[4], ss[4];
  int wid = t >> 6, lane = t & 63;
  if (lane == 0) sm[wid] = m;
  __syncthreads();
  float M = fmaxf(fmaxf(sm[0], sm[1]), fmaxf(sm[2], sm[3]));
  float e0 = __expf(v0 - M), e1 = __expf(v1 - M);
  float s = e0 + e1;
  #pragma unroll
  for (int off = 32; off; off >>= 1) s += __shfl_xor(s, off);
  if (lane == 0) ss[wid] = s;
  __syncthreads();
  float inv = 1.0f / ((ss[0] + ss[1]) + (ss[2] + ss[3]));
  qa[(long)bq * 512 + t]       = f2h(e0 * inv);
  qa[(long)bq * 512 + t + 256] = f2h(e1 * inv);
}

// ---------------- g3: PmaxA (LDS-free, K=64) || ctx, natural order ----------------

__global__ __launch_bounds__(256) void g3_kernel(
    const unsigned short* aq, const unsigned short* P3T, float* PmaxA,
    const unsigned short* qa, const float* Afeat, unsigned short* ctx)
{
  __shared__ char smem[16384];
  int bid = blockIdx.x;  // natural order (heterogeneous work types)
  if (bid < 1024) {
    // PmaxA: per batch M=512,N=1024,K=64, tile 128x128, fragments direct from global
    int bx = bid & 7, by = (bid >> 3) & 3, z = bid >> 5;
    int n0 = bx * 128, m0 = by * 128;
    const unsigned short* Aq = aq + (long)z * 32768;
    const unsigned short* Bp = P3T + (long)z * 65536;
    const int t = threadIdx.x, lane = t & 63;
    const int wid = t >> 6, wr = wid >> 1, wc = wid & 1;

    f32x4 acc[4][4];
    #pragma unroll
    for (int i = 0; i < 4; ++i)
      #pragma unroll
      for (int j = 0; j < 4; ++j)
        acc[i][j] = f32x4{0.f, 0.f, 0.f, 0.f};

    #pragma unroll
    for (int c = 0; c < 2; ++c) {
      f16x8 ah[4];
      #pragma unroll
      for (int mi = 0; mi < 4; ++mi) {
        int row = m0 + wr * 64 + mi * 16 + (lane & 15);
        ah[mi] = *(const f16x8*)(Aq + (long)row * 64 + c * 32 + (lane >> 4) * 8);
      }
      #pragma unroll
      for (int ni = 0; ni < 4; ++ni) {
        int rc = n0 + wc * 64 + ni * 16 + (lane & 15);
        f16x8 bh = *(const f16x8*)(Bp + (long)rc * 64 + c * 32 + (lane >> 4) * 8);
        #pragma unroll
        for (int mi = 0; mi < 4; ++mi)
          acc[mi][ni] = __builtin_amdgcn_mfma_f32_16x16x32_f16(ah[mi], bh, acc[mi][ni], 0, 0, 0);
      }
    }

    float* red = (float*)smem;  // [8][128] = 4KB
    #pragma unroll
    for (int ni = 0; ni < 4; ++ni) {
      float pm = 0.0f;  // relu floor
      #pragma unroll
      for (int mi = 0; mi < 4; ++mi)
        #pragma unroll
        for (int r = 0; r < 4; ++r)
          pm = fmaxf(pm, acc[mi][ni][r]);
      int g = wr * 4 + (lane >> 4);
      int col = wc * 64 + ni * 16 + (lane & 15);
      red[g * 128 + col] = pm;
    }
    __syncthreads();
    if (t < 128) {
      float m = red[t];
      #pragma unroll
      for (int g = 1; g < 8; ++g) m = fmaxf(m, red[g * 128 + t]);
      PmaxA[(long)(z * 4 + by) * 1024 + n0 + t] = m;
    }
  } else {           // ctx: per batch M=64,N=1024,K=512, tile 64x64, B = A fp32 (k-major)
    int b2 = bid - 1024;
    gemm_body<64, 64, 2, true>(smem, b2 & 15, 0, b2 >> 4,
        qa, nullptr, Afeat, nullptr, ctx,
        64, 1024, 512, 512, 1024, 1024, 32768L, 524288L, 65536L);
  }
}

// ---------------- g4: PmaxQ colmax + fused final combine ----------------

__global__ __launch_bounds__(256) void g4_kernel(
    const unsigned short* ctx, const unsigned short* W22T,
    const float* PmaxA, float* out)
{
  __shared__ char smem[16384];
  gemm_body<64, 64, 6, false>(smem, blockIdx.x, blockIdx.y, 0,
      ctx, W22T, PmaxA, out, nullptr,
      2048, 1024, 1024, 1024, 1024, 1024, 0, 0, 0);
}

// ---------------- launch ----------------

extern "C" void kernel_launch(void* const* d_in, const int* in_sizes, int n_in,
                              void* d_out, int out_size, void* d_ws, size_t ws_size,
                              hipStream_t stream) {
  const float* Afeat = (const float*)d_in[0];
  const float* Qfeat = (const float*)d_in[1];
  const float* W11   = (const float*)d_in[2];
  const float* W12   = (const float*)d_in[3];
  const float* W21   = (const float*)d_in[4];
  const float* W22   = (const float*)d_in[5];
  float* out = (float*)d_out;

  char* w = (char*)d_ws;
  auto alloc = [&](long bytes) { char* p = w; w += bytes; return p; };
  unsigned short* Q_hi  = (unsigned short*)alloc(4194304);
  unsigned short* Wcat  = (unsigned short*)alloc(4194304);   // [2048][1024] fp16: W11 ; W12^T
  unsigned short* W21T  = (unsigned short*)alloc(2097152);
  unsigned short* W22T  = (unsigned short*)alloc(2097152);
  unsigned short* Pcat  = (unsigned short*)alloc(8388608);   // [32][128][1024]
  unsigned short* P3T   = (unsigned short*)alloc(4194304);   // [32][1024][64]
  float*          Spar  = (float*)alloc(4194304);            // [32][512][64] qa scores
  unsigned short* aq    = (unsigned short*)alloc(2097152);   // [32][512][64]
  unsigned short* qa    = (unsigned short*)alloc(2097152);   // [32][64][512]
  unsigned short* ctx   = (unsigned short*)alloc(4194304);   // [32][64][1024]
  float*          PmaxA = (float*)alloc(524288);             // [128][1024]

  dim3 blk(256), tblk(32, 8);

  prep_all<<<dim3(32, 32, 6), tblk, 0, stream>>>(W11, W12, W21, W22, Qfeat,
                                                 Wcat, W21T, W22T, Q_hi);
  g1_kernel<<<768, blk, 0, stream>>>(Q_hi, Wcat, W21T, Pcat, P3T);
  g2_kernel<<<512, dim3(512), 0, stream>>>(Afeat, Pcat, aq, Spar);
  softmax_cols<<<2048, blk, 0, stream>>>(Spar, qa);
  g3_kernel<<<1536, blk, 0, stream>>>(aq, P3T, PmaxA, qa, Afeat, ctx);
  g4_kernel<<<dim3(16, 32), blk, 0, stream>>>(ctx, W22T, PmaxA, out);
}